// Round 9
// baseline (362.449 us; speedup 1.0000x reference)
//
#include <hip/hip_runtime.h>
#include <hip/hip_bf16.h>

#define SEQ 4096
#define HIDDEN 1280
#define NH 16
#define HD 80
#define QKV_N 3840
#define INV_SCALE 0.11180339887498949f
#define LOG2E 1.4426950408889634f

typedef __attribute__((ext_vector_type(8))) short bf16x8;
typedef __attribute__((ext_vector_type(4))) float f32x4;

__device__ __forceinline__ ushort f2bf(float f) {
  union { float f; unsigned u; } v; v.f = f;
  unsigned u = v.u;
  u += 0x7fff + ((u >> 16) & 1);   // RTNE
  return (ushort)(u >> 16);
}
__device__ __forceinline__ float bf2f(ushort h) {
  union { unsigned u; float f; } v; v.u = ((unsigned)h) << 16;
  return v.f;
}
__device__ __forceinline__ unsigned pk_bf16(float a, float b) {
  union { __hip_bfloat162 h; unsigned u; } v;
  v.h = __float22bfloat162_rn(make_float2(a, b));
  return v.u;
}
// async global->LDS, 16B per lane. LDS side must be base + lane*16 contiguous.
__device__ __forceinline__ void async16(void* lds, const void* g) {
  __builtin_amdgcn_global_load_lds(
      (const __attribute__((address_space(1))) unsigned*)g,
      (__attribute__((address_space(3))) unsigned*)(unsigned)(size_t)lds,
      16, 0, 0);
}

// -------- split fp32 -> bf16 hi (+optional lo), elementwise --------
__global__ __launch_bounds__(256)
void split_rows(const float* __restrict__ A, ushort* __restrict__ hi,
                ushort* __restrict__ lo, int n) {
  int i = (blockIdx.x * 256 + threadIdx.x) * 4;
  if (i >= n) return;
  float4 v = *(const float4*)&A[i];
  ushort h[4], l[4];
  float x[4] = {v.x, v.y, v.z, v.w};
#pragma unroll
  for (int t = 0; t < 4; ++t) {
    h[t] = f2bf(x[t]);
    l[t] = f2bf(x[t] - bf2f(h[t]));
  }
  *(ushort4*)&hi[i] = *(ushort4*)h;
  if (lo) *(ushort4*)&lo[i] = *(ushort4*)l;
}

// ---- split + transpose: W[K][N] -> hiT (+optional loT) [N][K] ----
__global__ __launch_bounds__(256)
void split_T(const float* __restrict__ W, ushort* __restrict__ hiT,
             ushort* __restrict__ loT, int K, int N) {
  __shared__ float T[32][33];
  const int k0 = blockIdx.y * 32, n0 = blockIdx.x * 32;
  for (int e = threadIdx.x; e < 1024; e += 256) {
    int r = e >> 5, c = e & 31;
    T[r][c] = W[(size_t)(k0 + r) * N + n0 + c];
  }
  __syncthreads();
  for (int e = threadIdx.x; e < 1024; e += 256) {
    int r = e >> 5, c = e & 31;        // r: n-index, c: k-index
    float x = T[c][r];
    ushort h = f2bf(x);
    size_t idx = (size_t)(n0 + r) * K + k0 + c;
    hiT[idx] = h;
    if (loT) loT[idx] = f2bf(x - bf2f(h));
  }
}

// ------- pure-bf16 GEMM: C[M,N] = A[M,K] @ B^T[N,K] + bias -------
// 128x128 tile, BK=64, 4 waves, DMA double-buffer + counted vmcnt + XCD swizzle.
__global__ __launch_bounds__(256, 2)
void gemm_bt_bf16(const ushort* __restrict__ Ab, const ushort* __restrict__ Bb,
                  const float* __restrict__ bias, float* __restrict__ C,
                  int M, int N, int K) {
  __shared__ __align__(16) ushort lds[32768];   // 2 bufs x (A0|A1|B0|B1, 8KB each)
  const int tid = threadIdx.x, lane = tid & 63, w = tid >> 6;
  const int m15 = lane & 15, g = lane >> 4;
  const int id = blockIdx.x;
  const int swz = (id & 7) * ((int)gridDim.x >> 3) + (id >> 3);
  const int nbx = N >> 7;
  const int m0 = (swz / nbx) * 128, n0 = (swz % nbx) * 128;
  const int wm = (w & 1) * 64, wn = (w >> 1) * 64;

  const ushort* stage_base =
      (w < 2) ? Ab + (size_t)m0 * K + (w & 1) * 32
              : Bb + (size_t)n0 * K + (w & 1) * 32;
  char* ldsb = (char*)lds;

  // bias first: oldest VMEM ops, drained by any later vmcnt
  float bv[4];
#pragma unroll
  for (int ni = 0; ni < 4; ++ni) bv[ni] = bias[n0 + wn + ni * 16 + m15];

  f32x4 acc[4][4];
#pragma unroll
  for (int i = 0; i < 4; ++i)
#pragma unroll
    for (int j = 0; j < 4; ++j) acc[i][j] = (f32x4){0.f, 0.f, 0.f, 0.f};

  const int NK = K >> 6;
  // prologue: tile 0 -> buf0
#pragma unroll
  for (int i = 0; i < 8; ++i) {
    int o = i * 1024 + lane * 16;      // byte offset within 8KB region
    int row = o >> 6, colb = o & 63;   // 64 B per row (32 bf16)
    async16(ldsb + w * 8192 + o, (const char*)(stage_base + (size_t)row * K) + colb);
  }
  for (int it = 0; it < NK; ++it) {
    const int cur = it & 1;
    const int kn = ((it + 1 < NK) ? it + 1 : it) * 64;
#pragma unroll
    for (int i = 0; i < 8; ++i) {
      int o = i * 1024 + lane * 16;
      int row = o >> 6, colb = o & 63;
      async16(ldsb + (cur ^ 1) * 32768 + w * 8192 + o,
              (const char*)(stage_base + (size_t)row * K + kn) + colb);
    }
    asm volatile("s_waitcnt vmcnt(8)" ::: "memory");
    __builtin_amdgcn_s_barrier();
    __builtin_amdgcn_sched_barrier(0);

    const ushort* L = lds + cur * 16384;
    bf16x8 ah[4][2], bh[4][2];
#pragma unroll
    for (int t = 0; t < 4; ++t) {
      ah[t][0] = *(const bf16x8*)&L[(wm + t * 16 + m15) * 32 + g * 8];
      ah[t][1] = *(const bf16x8*)&L[4096 + (wm + t * 16 + m15) * 32 + g * 8];
      bh[t][0] = *(const bf16x8*)&L[8192 + (wn + t * 16 + m15) * 32 + g * 8];
      bh[t][1] = *(const bf16x8*)&L[12288 + (wn + t * 16 + m15) * 32 + g * 8];
    }
#pragma unroll
    for (int mi = 0; mi < 4; ++mi)
#pragma unroll
      for (int ni = 0; ni < 4; ++ni) {
        acc[mi][ni] = __builtin_amdgcn_mfma_f32_16x16x32_bf16(ah[mi][0], bh[ni][0], acc[mi][ni], 0, 0, 0);
        acc[mi][ni] = __builtin_amdgcn_mfma_f32_16x16x32_bf16(ah[mi][1], bh[ni][1], acc[mi][ni], 0, 0, 0);
      }
    __builtin_amdgcn_s_barrier();
    __builtin_amdgcn_sched_barrier(0);
  }
#pragma unroll
  for (int mi = 0; mi < 4; ++mi)
#pragma unroll
    for (int ni = 0; ni < 4; ++ni) {
      int col = n0 + wn + ni * 16 + m15;
#pragma unroll
      for (int r = 0; r < 4; ++r)
        C[(size_t)(m0 + wm + mi * 16 + g * 4 + r) * N + col] = acc[mi][ni][r] + bv[ni];
    }
}

// ------- split-bf16 GEMM: C[M,N] = (Ah+Al)[M,K] @ (Bh+Bl)^T[N,K] + bias -------
__global__ __launch_bounds__(256, 2)
void gemm_bt_split(const ushort* __restrict__ Ah, const ushort* __restrict__ Al,
                   const ushort* __restrict__ Bh, const ushort* __restrict__ Bl,
                   const float* __restrict__ bias, float* __restrict__ C,
                   int M, int N, int K) {
  __shared__ __align__(16) ushort lds[32768];   // 2 bufs x (Ah|Al|Bh|Bl, 8KB each)
  const int tid = threadIdx.x, lane = tid & 63, w = tid >> 6;
  const int m15 = lane & 15, g = lane >> 4;
  const int id = blockIdx.x;
  const int swz = (id & 7) * ((int)gridDim.x >> 3) + (id >> 3);
  const int nbx = N >> 7;
  const int m0 = (swz / nbx) * 128, n0 = (swz % nbx) * 128;
  const int wm = (w & 1) * 64, wn = (w >> 1) * 64;

  const ushort* stage_base =
      (w == 0) ? Ah + (size_t)m0 * K :
      (w == 1) ? Al + (size_t)m0 * K :
      (w == 2) ? Bh + (size_t)n0 * K : Bl + (size_t)n0 * K;
  char* ldsb = (char*)lds;

  float bv[4];
#pragma unroll
  for (int ni = 0; ni < 4; ++ni) bv[ni] = bias[n0 + wn + ni * 16 + m15];

  f32x4 acc[4][4];
#pragma unroll
  for (int i = 0; i < 4; ++i)
#pragma unroll
    for (int j = 0; j < 4; ++j) acc[i][j] = (f32x4){0.f, 0.f, 0.f, 0.f};

  const int NK = K >> 5;
#pragma unroll
  for (int i = 0; i < 8; ++i) {
    int o = i * 1024 + lane * 16;
    int row = o >> 6, colb = o & 63;
    async16(ldsb + w * 8192 + o, (const char*)(stage_base + (size_t)row * K) + colb);
  }
  for (int it = 0; it < NK; ++it) {
    const int cur = it & 1;
    const int kn = ((it + 1 < NK) ? it + 1 : it) * 32;
#pragma unroll
    for (int i = 0; i < 8; ++i) {
      int o = i * 1024 + lane * 16;
      int row = o >> 6, colb = o & 63;
      async16(ldsb + (cur ^ 1) * 32768 + w * 8192 + o,
              (const char*)(stage_base + (size_t)row * K + kn) + colb);
    }
    asm volatile("s_waitcnt vmcnt(8)" ::: "memory");
    __builtin_amdgcn_s_barrier();
    __builtin_amdgcn_sched_barrier(0);

    const ushort* L = lds + cur * 16384;
    bf16x8 ah[4], al[4], bh[4], bl[4];
#pragma unroll
    for (int t = 0; t < 4; ++t) {
      ah[t] = *(const bf16x8*)&L[(wm + t * 16 + m15) * 32 + g * 8];
      al[t] = *(const bf16x8*)&L[4096 + (wm + t * 16 + m15) * 32 + g * 8];
      bh[t] = *(const bf16x8*)&L[8192 + (wn + t * 16 + m15) * 32 + g * 8];
      bl[t] = *(const bf16x8*)&L[12288 + (wn + t * 16 + m15) * 32 + g * 8];
    }
#pragma unroll
    for (int mi = 0; mi < 4; ++mi)
#pragma unroll
      for (int ni = 0; ni < 4; ++ni) {
        acc[mi][ni] = __builtin_amdgcn_mfma_f32_16x16x32_bf16(ah[mi], bh[ni], acc[mi][ni], 0, 0, 0);
        acc[mi][ni] = __builtin_amdgcn_mfma_f32_16x16x32_bf16(ah[mi], bl[ni], acc[mi][ni], 0, 0, 0);
        acc[mi][ni] = __builtin_amdgcn_mfma_f32_16x16x32_bf16(al[mi], bh[ni], acc[mi][ni], 0, 0, 0);
      }
    __builtin_amdgcn_s_barrier();
    __builtin_amdgcn_sched_barrier(0);
  }
#pragma unroll
  for (int mi = 0; mi < 4; ++mi)
#pragma unroll
    for (int ni = 0; ni < 4; ++ni) {
      int col = n0 + wn + ni * 16 + m15;
#pragma unroll
      for (int r = 0; r < 4; ++r)
        C[(size_t)(m0 + wm + mi * 16 + g * 4 + r) * N + col] = acc[mi][ni][r] + bv[ni];
    }
}

// ------------- rotary + cast: Qb/Kb [h][s][96] (zero-padded) -------------
__global__ __launch_bounds__(256)
void rotary_qk(const float* __restrict__ qkv, const float* __restrict__ cosb,
               const float* __restrict__ sinb, ushort* __restrict__ Qb,
               ushort* __restrict__ Kb) {
  int id = blockIdx.x * 256 + threadIdx.x;
  int j = id % 48;
  int h = (id / 48) % NH;
  int s = id / (48 * NH);
  size_t qrow = (size_t)((h << 12) + s) * 96;
  if (j < 40) {
    size_t base = (size_t)s * QKV_N + h * HD;
    float c1 = cosb[s * HD + j],      s1 = sinb[s * HD + j];
    float c2 = cosb[s * HD + j + 40], s2 = sinb[s * HD + j + 40];
    const float QS = INV_SCALE * LOG2E;
    float q1 = qkv[base + j], q2 = qkv[base + j + 40];
    Qb[qrow + j]      = f2bf((q1 * c1 - q2 * s1) * QS);
    Qb[qrow + j + 40] = f2bf((q2 * c2 + q1 * s2) * QS);
    float k1 = qkv[base + HIDDEN + j], k2 = qkv[base + HIDDEN + j + 40];
    Kb[qrow + j]      = f2bf(k1 * c1 - k2 * s1);
    Kb[qrow + j + 40] = f2bf(k2 * c2 + k1 * s2);
  } else {
    int d = 80 + (j - 40) * 2;
    Qb[qrow + d] = 0; Qb[qrow + d + 1] = 0;
    Kb[qrow + d] = 0; Kb[qrow + d + 1] = 0;
  }
}

// ------------- V transpose: qkv v-section -> VbT[h][80][4096] bf16 -------------
__global__ __launch_bounds__(256)
void v_trans(const float* __restrict__ qkv, ushort* __restrict__ VbT) {
  __shared__ float T[64][81];
  const int h = blockIdx.y, s0 = blockIdx.x * 64;
  for (int e = threadIdx.x; e < 5120; e += 256) {
    int r = e / 80, d = e % 80;
    T[r][d] = qkv[(size_t)(s0 + r) * QKV_N + 2 * HIDDEN + h * HD + d];
  }
  __syncthreads();
  for (int e = threadIdx.x; e < 2560; e += 256) {
    int d = e >> 5, rp = (e & 31) * 2;
    ushort2 p;
    p.x = f2bf(T[rp][d]);
    p.y = f2bf(T[rp + 1][d]);
    *(ushort2*)&VbT[(size_t)h * 80 * SEQ + (size_t)d * SEQ + s0 + rp] = p;
  }
}

// ---- flash attention, bf16 MFMA, fixed-max softmax, fused normalize ----
// grid 512 x 256 threads (4 waves x 32 q-rows).
// R13: XCD-aware block swizzle -- logical = (idp&7)*64 + (idp>>3) gives XCD k
// logical blocks [64k,64k+64) = heads 2k,2k+1, so each XCD's K/V working set
// is 2.9MB < 4MB L2 (was: every XCD touched all 16 heads = 23MB, L2 thrash;
// 940MB of staging traffic served from L3). Also: T5 setprio around MFMA
// clusters; V fragments hoisted above the lgkmcnt(0) so their read latency
// hides under the exp2/pack phase.
// Pipeline per iter (R8, verified): issue 7 DMA chunks for t+1 ->
// s_waitcnt vmcnt(7) -> s_barrier -> compute t -> s_barrier.
// LDS 79,872 B -> 2 blocks/CU.
#define LPS 88    // Ps row stride (ushort)
#define LKS 104   // Ks row stride (ushort): 208 B = 13 chunks; 52 dw == 20 mod 32
#define LVS 88    // Vt row stride (ushort): 176 B = 11 chunks; 44 dw == 12 mod 32
__global__ __launch_bounds__(256, 2)
void attn_mfma(const ushort* __restrict__ Qb, const ushort* __restrict__ Kb,
               const ushort* __restrict__ VbT, ushort* __restrict__ ao_hi,
               ushort* __restrict__ ao_lo) {
  // [0,11264) ushorts: Ps[128][LPS] (22528 B)
  // buf b at byte 22528 + b*28672: Ks 64x[LKS] (13312 B) | Vt 80x[LVS] (14080 B)
  //   | pad 1280 B.  Total 22528 + 2*28672 = 79872 B.
  __shared__ __align__(16) ushort lds[39936];
  ushort* Ps = lds;
  char* ldsb = (char*)lds;

  const int tid = threadIdx.x, lane = tid & 63, w = tid >> 6;
  const int m15 = lane & 15, g = lane >> 4;
  const int idp = blockIdx.x;
  const int logical = (idp & 7) * 64 + (idp >> 3);   // XCD-contiguous
  const int h = logical >> 5, q0 = (logical & 31) * 128;
  const size_t hq = (size_t)h * SEQ * 96;
  const ushort* Qg = Qb + hq + (size_t)q0 * 96;
  const char* Kg = (const char*)(Kb + hq);
  const ushort* Vg = VbT + (size_t)h * 80 * SEQ;

  // ---- Q fragments straight from global (one-time, 6x16B per lane)
  bf16x8 qf[2][3];
#pragma unroll
  for (int mi = 0; mi < 2; ++mi)
#pragma unroll
    for (int c = 0; c < 3; ++c)
      qf[mi][c] = *(const bf16x8*)&Qg[(w * 32 + mi * 16 + m15) * 96 + c * 32 + g * 8];

  // ---- DMA source map: 1792 16B chunks/tile (K 832 | V 880 | pad 80), 7/thread.
  const char* sbase[7];
  int sstride[7];
#pragma unroll
  for (int i = 0; i < 7; ++i) {
    int c = tid + i * 256;
    if (c < 832) {
      int r = c / 13, cc = c - r * 13;
      sbase[i] = Kg + r * 192 + (cc == 12 ? 176 : cc * 16);
      sstride[i] = 192;                      // K tile advances kbase*192 bytes
    } else if (c < 1712) {
      int cv = c - 832;
      int r = cv / 11, cc = cv - r * 11;
      sbase[i] = (const char*)(Vg + (size_t)r * SEQ) + (cc >= 8 ? 112 : cc * 16);
      sstride[i] = 2;                        // V tile advances kbase*2 bytes
    } else {
      sbase[i] = Kg;
      sstride[i] = 192;
    }
  }
  const int dbase = 22528 + tid * 16;        // Ps bytes + lane-linear chunks

  // ---- prologue: issue DMA for tile 0 into buf0
#pragma unroll
  for (int i = 0; i < 7; ++i)
    async16(ldsb + dbase + i * 4096, sbase[i]);

  f32x4 o_[2][5];
#pragma unroll
  for (int mi = 0; mi < 2; ++mi)
#pragma unroll
    for (int n = 0; n < 5; ++n) o_[mi][n] = (f32x4){0.f, 0.f, 0.f, 0.f};
  float l_part[2] = {0.f, 0.f};

  const int NT = SEQ / 64;
  for (int kt = 0; kt < NT; ++kt) {
    const int cur = kt & 1;
    // ---- issue DMA for tile t+1 into buf^1 (clamped on last iter)
    {
      const size_t kn = (size_t)(((kt + 1 < NT) ? kt + 1 : kt) * 64);
      const int db = dbase + (cur ^ 1) * 28672;
#pragma unroll
      for (int i = 0; i < 7; ++i)
        async16(ldsb + db + i * 4096, sbase[i] + kn * sstride[i]);
    }
    // ---- wait own tile-t DMAs (t+1's 7 stay in flight), publish via barrier
    asm volatile("s_waitcnt vmcnt(7)" ::: "memory");
    __builtin_amdgcn_s_barrier();
    __builtin_amdgcn_sched_barrier(0);

    ushort* Ks = lds + 11264 + cur * 14336;
    ushort* Vt = Ks + 6656;

    // ---- S^T = K Q^T (log2-scaled): rows=key, col=q
    f32x4 st[2][4];
#pragma unroll
    for (int mi = 0; mi < 2; ++mi)
#pragma unroll
      for (int j = 0; j < 4; ++j) st[mi][j] = (f32x4){0.f, 0.f, 0.f, 0.f};
    __builtin_amdgcn_s_setprio(1);
#pragma unroll
    for (int j = 0; j < 4; ++j)
#pragma unroll
      for (int c = 0; c < 3; ++c) {
        bf16x8 kf = *(const bf16x8*)&Ks[(j * 16 + m15) * LKS + c * 32 + g * 8];
        st[0][j] = __builtin_amdgcn_mfma_f32_16x16x32_bf16(kf, qf[0][c], st[0][j], 0, 0, 0);
        st[1][j] = __builtin_amdgcn_mfma_f32_16x16x32_bf16(kf, qf[1][c], st[1][j], 0, 0, 0);
      }
    __builtin_amdgcn_s_setprio(0);
    // ---- hoist V fragments: issue reads now, latency hides under exp2/pack
    bf16x8 vfr[2][5];
#pragma unroll
    for (int kc = 0; kc < 2; ++kc)
#pragma unroll
      for (int n = 0; n < 5; ++n)
        vfr[kc][n] = *(const bf16x8*)&Vt[(n * 16 + m15) * LVS + kc * 32 + g * 8];
    // ---- p = exp2(s); accumulate l per-lane; pack & store P^T -> Ps[q][key]
#pragma unroll
    for (int mi = 0; mi < 2; ++mi) {
      float ls = 0.f;
#pragma unroll
      for (int j = 0; j < 4; ++j) {
        float p0 = __builtin_amdgcn_exp2f(st[mi][j][0]);
        float p1 = __builtin_amdgcn_exp2f(st[mi][j][1]);
        float p2 = __builtin_amdgcn_exp2f(st[mi][j][2]);
        float p3 = __builtin_amdgcn_exp2f(st[mi][j][3]);
        ls += (p0 + p1) + (p2 + p3);
        uint2 pw;
        pw.x = pk_bf16(p0, p1);
        pw.y = pk_bf16(p2, p3);
        *(uint2*)&Ps[(w * 32 + mi * 16 + m15) * LPS + j * 16 + g * 4] = pw;
      }
      l_part[mi] += ls;
    }
    // Ps rows are wave-private; order LDS writes before cross-lane reads.
    asm volatile("s_waitcnt lgkmcnt(0)" ::: "memory");
    __builtin_amdgcn_sched_barrier(0);
    // ---- O += P V
    __builtin_amdgcn_s_setprio(1);
#pragma unroll
    for (int kc = 0; kc < 2; ++kc) {
      bf16x8 pf0 = *(const bf16x8*)&Ps[(w * 32 + m15) * LPS + kc * 32 + g * 8];
      bf16x8 pf1 = *(const bf16x8*)&Ps[(w * 32 + 16 + m15) * LPS + kc * 32 + g * 8];
#pragma unroll
      for (int n = 0; n < 5; ++n) {
        o_[0][n] = __builtin_amdgcn_mfma_f32_16x16x32_bf16(pf0, vfr[kc][n], o_[0][n], 0, 0, 0);
        o_[1][n] = __builtin_amdgcn_mfma_f32_16x16x32_bf16(pf1, vfr[kc][n], o_[1][n], 0, 0, 0);
      }
    }
    __builtin_amdgcn_s_setprio(0);
    // ---- all waves done reading buf[cur] before next iter's DMA overwrites it
    __builtin_amdgcn_s_barrier();
    __builtin_amdgcn_sched_barrier(0);
  }
  // ---- l: reduce over g-groups; redistribute to row-owners; normalize; split
  float linv[2][4];
#pragma unroll
  for (int mi = 0; mi < 2; ++mi) {
    float t = l_part[mi];
    t += __shfl_xor(t, 16);
    t += __shfl_xor(t, 32);   // every lane: full l for q = w*32+mi*16+m15
#pragma unroll
    for (int r = 0; r < 4; ++r)
      linv[mi][r] = 1.f / __shfl(t, g * 4 + r);   // l for q-row g*4+r
  }
#pragma unroll
  for (int mi = 0; mi < 2; ++mi)
#pragma unroll
    for (int r = 0; r < 4; ++r) {
      int grow = q0 + w * 32 + mi * 16 + g * 4 + r;
      size_t base = (size_t)grow * HIDDEN + h * HD + m15;
#pragma unroll
      for (int n = 0; n < 5; ++n) {
        float x = o_[mi][n][r] * linv[mi][r];
        ushort hi = f2bf(x);
        ao_hi[base + n * 16] = hi;
        ao_lo[base + n * 16] = f2bf(x - bf2f(hi));
      }
    }
}

extern "C" void kernel_launch(void* const* d_in, const int* in_sizes, int n_in,
                              void* d_out, int out_size, void* d_ws, size_t ws_size,
                              hipStream_t stream) {
  const float* x      = (const float*)d_in[0];
  const float* cosb   = (const float*)d_in[1];
  const float* sinb   = (const float*)d_in[2];
  const float* w_qkv  = (const float*)d_in[3];
  const float* b_qkv  = (const float*)d_in[4];
  const float* w_proj = (const float*)d_in[5];
  const float* b_proj = (const float*)d_in[6];
  float* out = (float*)d_out;

  // workspace layout (aliased; all kernels strictly ordered on `stream`):
  char* ws = (char*)d_ws;
  float*  qkv   = (float*)ws;                    // 60 MB; dead after v_trans
  ushort* ao_hi = (ushort*)(ws + 42467328);      // 10,485,760 (over dead qkv)
  ushort* ao_lo = (ushort*)(ws + 52953088);      // 10,485,760
  size_t o = 62914560;
  ushort* xhi = (ushort*)(ws + o);               // 10.5 MB (hi only; no lo needed)
  ushort* Qb  = (ushort*)(ws + o);               // alias x-region after gemm1
  o += 20971520;
  ushort* wqT_h = (ushort*)(ws + o);             // 9.83 MB (hi only)
  ushort* Kb    = (ushort*)(ws + o);             // alias wqT after gemm1
  o += 19660800;
  ushort* VbT   = (ushort*)(ws + o); o += 10485760;   // 10.5 MB
  ushort* wpT_h = (ushort*)(ws + o); o += 3276800;
  ushort* wpT_l = (ushort*)(ws + o);             // total ~120.6 MB

  // 1) casts / splits
  split_rows<<<SEQ * HIDDEN / 1024, 256, 0, stream>>>(x, xhi, nullptr, SEQ * HIDDEN);
  split_T<<<dim3(QKV_N / 32, HIDDEN / 32), 256, 0, stream>>>(w_qkv, wqT_h, nullptr, HIDDEN, QKV_N);
  split_T<<<dim3(HIDDEN / 32, HIDDEN / 32), 256, 0, stream>>>(w_proj, wpT_h, wpT_l, HIDDEN, HIDDEN);
  // 2) qkv = x @ w_qkv + b_qkv   (XCD-swizzled 1D grid: 30x32=960 blocks)
  gemm_bt_bf16<<<(QKV_N / 128) * (SEQ / 128), 256, 0, stream>>>(
      xhi, wqT_h, b_qkv, qkv, SEQ, QKV_N, HIDDEN);
  // 3) rotary -> Qb/Kb; V transpose -> VbT  (qkv dead afterwards)
  rotary_qk<<<SEQ * NH * 48 / 256, 256, 0, stream>>>(qkv, cosb, sinb, Qb, Kb);
  v_trans<<<dim3(SEQ / 64, NH), 256, 0, stream>>>(qkv, VbT);
  // 4) attention + fused normalize/split -> ao_hi/ao_lo (XCD-swizzled 1D grid)
  attn_mfma<<<(SEQ / 128) * NH, 256, 0, stream>>>(Qb, Kb, VbT, ao_hi, ao_lo);
  // 5) out = attn @ w_proj + b_proj  (XCD-swizzled 1D grid: 10x32=320 blocks)
  gemm_bt_split<<<(HIDDEN / 128) * (SEQ / 128), 256, 0, stream>>>(
      ao_hi, ao_lo, wpT_h, wpT_l, b_proj, out, SEQ, HIDDEN, HIDDEN);
}

// Round 10
// 346.543 us; speedup vs baseline: 1.0459x; 1.0459x over previous
//
#include <hip/hip_runtime.h>
#include <hip/hip_bf16.h>

#define SEQ 4096
#define HIDDEN 1280
#define NH 16
#define HD 80
#define QKV_N 3840
#define INV_SCALE 0.11180339887498949f
#define LOG2E 1.4426950408889634f

typedef __attribute__((ext_vector_type(8))) short bf16x8;
typedef __attribute__((ext_vector_type(4))) float f32x4;

__device__ __forceinline__ ushort f2bf(float f) {
  union { float f; unsigned u; } v; v.f = f;
  unsigned u = v.u;
  u += 0x7fff + ((u >> 16) & 1);   // RTNE
  return (ushort)(u >> 16);
}
__device__ __forceinline__ float bf2f(ushort h) {
  union { unsigned u; float f; } v; v.u = ((unsigned)h) << 16;
  return v.f;
}
__device__ __forceinline__ unsigned pk_bf16(float a, float b) {
  union { __hip_bfloat162 h; unsigned u; } v;
  v.h = __float22bfloat162_rn(make_float2(a, b));
  return v.u;
}
// async global->LDS, 16B per lane. LDS side must be base + lane*16 contiguous.
__device__ __forceinline__ void async16(void* lds, const void* g) {
  __builtin_amdgcn_global_load_lds(
      (const __attribute__((address_space(1))) unsigned*)g,
      (__attribute__((address_space(3))) unsigned*)(unsigned)(size_t)lds,
      16, 0, 0);
}

// -------- split fp32 -> bf16 hi (+optional lo), elementwise --------
__global__ __launch_bounds__(256)
void split_rows(const float* __restrict__ A, ushort* __restrict__ hi,
                ushort* __restrict__ lo, int n) {
  int i = (blockIdx.x * 256 + threadIdx.x) * 4;
  if (i >= n) return;
  float4 v = *(const float4*)&A[i];
  ushort h[4], l[4];
  float x[4] = {v.x, v.y, v.z, v.w};
#pragma unroll
  for (int t = 0; t < 4; ++t) {
    h[t] = f2bf(x[t]);
    l[t] = f2bf(x[t] - bf2f(h[t]));
  }
  *(ushort4*)&hi[i] = *(ushort4*)h;
  if (lo) *(ushort4*)&lo[i] = *(ushort4*)l;
}

// ---- split + transpose: W[K][N] -> hiT (+optional loT) [N][K] ----
__global__ __launch_bounds__(256)
void split_T(const float* __restrict__ W, ushort* __restrict__ hiT,
             ushort* __restrict__ loT, int K, int N) {
  __shared__ float T[32][33];
  const int k0 = blockIdx.y * 32, n0 = blockIdx.x * 32;
  for (int e = threadIdx.x; e < 1024; e += 256) {
    int r = e >> 5, c = e & 31;
    T[r][c] = W[(size_t)(k0 + r) * N + n0 + c];
  }
  __syncthreads();
  for (int e = threadIdx.x; e < 1024; e += 256) {
    int r = e >> 5, c = e & 31;        // r: n-index, c: k-index
    float x = T[c][r];
    ushort h = f2bf(x);
    size_t idx = (size_t)(n0 + r) * K + k0 + c;
    hiT[idx] = h;
    if (loT) loT[idx] = f2bf(x - bf2f(h));
  }
}

// ------- pure-bf16 GEMM: C[M,N] = A[M,K] @ B^T[N,K] + bias -------
// 128x128 tile, BK=64, 4 waves, DMA double-buffer + counted vmcnt + XCD swizzle.
__global__ __launch_bounds__(256, 2)
void gemm_bt_bf16(const ushort* __restrict__ Ab, const ushort* __restrict__ Bb,
                  const float* __restrict__ bias, float* __restrict__ C,
                  int M, int N, int K) {
  __shared__ __align__(16) ushort lds[32768];   // 2 bufs x (A0|A1|B0|B1, 8KB each)
  const int tid = threadIdx.x, lane = tid & 63, w = tid >> 6;
  const int m15 = lane & 15, g = lane >> 4;
  const int id = blockIdx.x;
  const int swz = (id & 7) * ((int)gridDim.x >> 3) + (id >> 3);
  const int nbx = N >> 7;
  const int m0 = (swz / nbx) * 128, n0 = (swz % nbx) * 128;
  const int wm = (w & 1) * 64, wn = (w >> 1) * 64;

  const ushort* stage_base =
      (w < 2) ? Ab + (size_t)m0 * K + (w & 1) * 32
              : Bb + (size_t)n0 * K + (w & 1) * 32;
  char* ldsb = (char*)lds;

  // bias first: oldest VMEM ops, drained by any later vmcnt
  float bv[4];
#pragma unroll
  for (int ni = 0; ni < 4; ++ni) bv[ni] = bias[n0 + wn + ni * 16 + m15];

  f32x4 acc[4][4];
#pragma unroll
  for (int i = 0; i < 4; ++i)
#pragma unroll
    for (int j = 0; j < 4; ++j) acc[i][j] = (f32x4){0.f, 0.f, 0.f, 0.f};

  const int NK = K >> 6;
  // prologue: tile 0 -> buf0
#pragma unroll
  for (int i = 0; i < 8; ++i) {
    int o = i * 1024 + lane * 16;      // byte offset within 8KB region
    int row = o >> 6, colb = o & 63;   // 64 B per row (32 bf16)
    async16(ldsb + w * 8192 + o, (const char*)(stage_base + (size_t)row * K) + colb);
  }
  for (int it = 0; it < NK; ++it) {
    const int cur = it & 1;
    const int kn = ((it + 1 < NK) ? it + 1 : it) * 64;
#pragma unroll
    for (int i = 0; i < 8; ++i) {
      int o = i * 1024 + lane * 16;
      int row = o >> 6, colb = o & 63;
      async16(ldsb + (cur ^ 1) * 32768 + w * 8192 + o,
              (const char*)(stage_base + (size_t)row * K + kn) + colb);
    }
    asm volatile("s_waitcnt vmcnt(8)" ::: "memory");
    __builtin_amdgcn_s_barrier();
    __builtin_amdgcn_sched_barrier(0);

    const ushort* L = lds + cur * 16384;
    bf16x8 ah[4][2], bh[4][2];
#pragma unroll
    for (int t = 0; t < 4; ++t) {
      ah[t][0] = *(const bf16x8*)&L[(wm + t * 16 + m15) * 32 + g * 8];
      ah[t][1] = *(const bf16x8*)&L[4096 + (wm + t * 16 + m15) * 32 + g * 8];
      bh[t][0] = *(const bf16x8*)&L[8192 + (wn + t * 16 + m15) * 32 + g * 8];
      bh[t][1] = *(const bf16x8*)&L[12288 + (wn + t * 16 + m15) * 32 + g * 8];
    }
#pragma unroll
    for (int mi = 0; mi < 4; ++mi)
#pragma unroll
      for (int ni = 0; ni < 4; ++ni) {
        acc[mi][ni] = __builtin_amdgcn_mfma_f32_16x16x32_bf16(ah[mi][0], bh[ni][0], acc[mi][ni], 0, 0, 0);
        acc[mi][ni] = __builtin_amdgcn_mfma_f32_16x16x32_bf16(ah[mi][1], bh[ni][1], acc[mi][ni], 0, 0, 0);
      }
    __builtin_amdgcn_s_barrier();
    __builtin_amdgcn_sched_barrier(0);
  }
#pragma unroll
  for (int mi = 0; mi < 4; ++mi)
#pragma unroll
    for (int ni = 0; ni < 4; ++ni) {
      int col = n0 + wn + ni * 16 + m15;
#pragma unroll
      for (int r = 0; r < 4; ++r)
        C[(size_t)(m0 + wm + mi * 16 + g * 4 + r) * N + col] = acc[mi][ni][r] + bv[ni];
    }
}

// ------- split-bf16 GEMM: C[M,N] = (Ah+Al)[M,K] @ (Bh+Bl)^T[N,K] + bias -------
__global__ __launch_bounds__(256, 2)
void gemm_bt_split(const ushort* __restrict__ Ah, const ushort* __restrict__ Al,
                   const ushort* __restrict__ Bh, const ushort* __restrict__ Bl,
                   const float* __restrict__ bias, float* __restrict__ C,
                   int M, int N, int K) {
  __shared__ __align__(16) ushort lds[32768];   // 2 bufs x (Ah|Al|Bh|Bl, 8KB each)
  const int tid = threadIdx.x, lane = tid & 63, w = tid >> 6;
  const int m15 = lane & 15, g = lane >> 4;
  const int id = blockIdx.x;
  const int swz = (id & 7) * ((int)gridDim.x >> 3) + (id >> 3);
  const int nbx = N >> 7;
  const int m0 = (swz / nbx) * 128, n0 = (swz % nbx) * 128;
  const int wm = (w & 1) * 64, wn = (w >> 1) * 64;

  const ushort* stage_base =
      (w == 0) ? Ah + (size_t)m0 * K :
      (w == 1) ? Al + (size_t)m0 * K :
      (w == 2) ? Bh + (size_t)n0 * K : Bl + (size_t)n0 * K;
  char* ldsb = (char*)lds;

  float bv[4];
#pragma unroll
  for (int ni = 0; ni < 4; ++ni) bv[ni] = bias[n0 + wn + ni * 16 + m15];

  f32x4 acc[4][4];
#pragma unroll
  for (int i = 0; i < 4; ++i)
#pragma unroll
    for (int j = 0; j < 4; ++j) acc[i][j] = (f32x4){0.f, 0.f, 0.f, 0.f};

  const int NK = K >> 5;
#pragma unroll
  for (int i = 0; i < 8; ++i) {
    int o = i * 1024 + lane * 16;
    int row = o >> 6, colb = o & 63;
    async16(ldsb + w * 8192 + o, (const char*)(stage_base + (size_t)row * K) + colb);
  }
  for (int it = 0; it < NK; ++it) {
    const int cur = it & 1;
    const int kn = ((it + 1 < NK) ? it + 1 : it) * 32;
#pragma unroll
    for (int i = 0; i < 8; ++i) {
      int o = i * 1024 + lane * 16;
      int row = o >> 6, colb = o & 63;
      async16(ldsb + (cur ^ 1) * 32768 + w * 8192 + o,
              (const char*)(stage_base + (size_t)row * K + kn) + colb);
    }
    asm volatile("s_waitcnt vmcnt(8)" ::: "memory");
    __builtin_amdgcn_s_barrier();
    __builtin_amdgcn_sched_barrier(0);

    const ushort* L = lds + cur * 16384;
    bf16x8 ah[4], al[4], bh[4], bl[4];
#pragma unroll
    for (int t = 0; t < 4; ++t) {
      ah[t] = *(const bf16x8*)&L[(wm + t * 16 + m15) * 32 + g * 8];
      al[t] = *(const bf16x8*)&L[4096 + (wm + t * 16 + m15) * 32 + g * 8];
      bh[t] = *(const bf16x8*)&L[8192 + (wn + t * 16 + m15) * 32 + g * 8];
      bl[t] = *(const bf16x8*)&L[12288 + (wn + t * 16 + m15) * 32 + g * 8];
    }
#pragma unroll
    for (int mi = 0; mi < 4; ++mi)
#pragma unroll
      for (int ni = 0; ni < 4; ++ni) {
        acc[mi][ni] = __builtin_amdgcn_mfma_f32_16x16x32_bf16(ah[mi], bh[ni], acc[mi][ni], 0, 0, 0);
        acc[mi][ni] = __builtin_amdgcn_mfma_f32_16x16x32_bf16(ah[mi], bl[ni], acc[mi][ni], 0, 0, 0);
        acc[mi][ni] = __builtin_amdgcn_mfma_f32_16x16x32_bf16(al[mi], bh[ni], acc[mi][ni], 0, 0, 0);
      }
    __builtin_amdgcn_s_barrier();
    __builtin_amdgcn_sched_barrier(0);
  }
#pragma unroll
  for (int mi = 0; mi < 4; ++mi)
#pragma unroll
    for (int ni = 0; ni < 4; ++ni) {
      int col = n0 + wn + ni * 16 + m15;
#pragma unroll
      for (int r = 0; r < 4; ++r)
        C[(size_t)(m0 + wm + mi * 16 + g * 4 + r) * N + col] = acc[mi][ni][r] + bv[ni];
    }
}

// ------------- rotary + cast: Qb/Kb [h][s][96] (zero-padded) -------------
__global__ __launch_bounds__(256)
void rotary_qk(const float* __restrict__ qkv, const float* __restrict__ cosb,
               const float* __restrict__ sinb, ushort* __restrict__ Qb,
               ushort* __restrict__ Kb) {
  int id = blockIdx.x * 256 + threadIdx.x;
  int j = id % 48;
  int h = (id / 48) % NH;
  int s = id / (48 * NH);
  size_t qrow = (size_t)((h << 12) + s) * 96;
  if (j < 40) {
    size_t base = (size_t)s * QKV_N + h * HD;
    float c1 = cosb[s * HD + j],      s1 = sinb[s * HD + j];
    float c2 = cosb[s * HD + j + 40], s2 = sinb[s * HD + j + 40];
    const float QS = INV_SCALE * LOG2E;
    float q1 = qkv[base + j], q2 = qkv[base + j + 40];
    Qb[qrow + j]      = f2bf((q1 * c1 - q2 * s1) * QS);
    Qb[qrow + j + 40] = f2bf((q2 * c2 + q1 * s2) * QS);
    float k1 = qkv[base + HIDDEN + j], k2 = qkv[base + HIDDEN + j + 40];
    Kb[qrow + j]      = f2bf(k1 * c1 - k2 * s1);
    Kb[qrow + j + 40] = f2bf(k2 * c2 + k1 * s2);
  } else {
    int d = 80 + (j - 40) * 2;
    Qb[qrow + d] = 0; Qb[qrow + d + 1] = 0;
    Kb[qrow + d] = 0; Kb[qrow + d + 1] = 0;
  }
}

// ------------- V transpose: qkv v-section -> VbT[h][80][4096] bf16 -------------
__global__ __launch_bounds__(256)
void v_trans(const float* __restrict__ qkv, ushort* __restrict__ VbT) {
  __shared__ float T[64][81];
  const int h = blockIdx.y, s0 = blockIdx.x * 64;
  for (int e = threadIdx.x; e < 5120; e += 256) {
    int r = e / 80, d = e % 80;
    T[r][d] = qkv[(size_t)(s0 + r) * QKV_N + 2 * HIDDEN + h * HD + d];
  }
  __syncthreads();
  for (int e = threadIdx.x; e < 2560; e += 256) {
    int d = e >> 5, rp = (e & 31) * 2;
    ushort2 p;
    p.x = f2bf(T[rp][d]);
    p.y = f2bf(T[rp + 1][d]);
    *(ushort2*)&VbT[(size_t)h * 80 * SEQ + (size_t)d * SEQ + s0 + rp] = p;
  }
}

// ---- flash attention, bf16 MFMA, fixed-max softmax, fused normalize ----
// grid 512 x 256 threads (4 waves x 32 q-rows).
// R14: isolation round. R13 bundled {XCD swizzle, setprio, V-hoist} and
// regressed attn 129->140 while FETCH collapsed 96->17.5MB (swizzle's L2
// mechanism proven). This keeps ONLY the swizzle; setprio reverted (m190:
// hurts lockstep barrier-synced structures) and V-hoist reverted (extended
// LDS-read live ranges for no benefit). Body is the verified R12 code.
// Pipeline per iter (R8): issue 7 DMA chunks for t+1 -> s_waitcnt vmcnt(7)
// -> s_barrier -> compute t -> s_barrier. LDS 79,872 B -> 2 blocks/CU.
#define LPS 88    // Ps row stride (ushort)
#define LKS 104   // Ks row stride (ushort): 208 B = 13 chunks; 52 dw == 20 mod 32
#define LVS 88    // Vt row stride (ushort): 176 B = 11 chunks; 44 dw == 12 mod 32
__global__ __launch_bounds__(256, 2)
void attn_mfma(const ushort* __restrict__ Qb, const ushort* __restrict__ Kb,
               const ushort* __restrict__ VbT, ushort* __restrict__ ao_hi,
               ushort* __restrict__ ao_lo) {
  // [0,11264) ushorts: Ps[128][LPS] (22528 B)
  // buf b at byte 22528 + b*28672: Ks 64x[LKS] (13312 B) | Vt 80x[LVS] (14080 B)
  //   | pad 1280 B.  Total 22528 + 2*28672 = 79872 B.
  __shared__ __align__(16) ushort lds[39936];
  ushort* Ps = lds;
  char* ldsb = (char*)lds;

  const int tid = threadIdx.x, lane = tid & 63, w = tid >> 6;
  const int m15 = lane & 15, g = lane >> 4;
  const int idp = blockIdx.x;
  const int logical = (idp & 7) * 64 + (idp >> 3);   // XCD-contiguous
  const int h = logical >> 5, q0 = (logical & 31) * 128;
  const size_t hq = (size_t)h * SEQ * 96;
  const ushort* Qg = Qb + hq + (size_t)q0 * 96;
  const char* Kg = (const char*)(Kb + hq);
  const ushort* Vg = VbT + (size_t)h * 80 * SEQ;

  // ---- Q fragments straight from global (one-time, 6x16B per lane)
  bf16x8 qf[2][3];
#pragma unroll
  for (int mi = 0; mi < 2; ++mi)
#pragma unroll
    for (int c = 0; c < 3; ++c)
      qf[mi][c] = *(const bf16x8*)&Qg[(w * 32 + mi * 16 + m15) * 96 + c * 32 + g * 8];

  // ---- DMA source map: 1792 16B chunks/tile (K 832 | V 880 | pad 80), 7/thread.
  const char* sbase[7];
  int sstride[7];
#pragma unroll
  for (int i = 0; i < 7; ++i) {
    int c = tid + i * 256;
    if (c < 832) {
      int r = c / 13, cc = c - r * 13;
      sbase[i] = Kg + r * 192 + (cc == 12 ? 176 : cc * 16);
      sstride[i] = 192;                      // K tile advances kbase*192 bytes
    } else if (c < 1712) {
      int cv = c - 832;
      int r = cv / 11, cc = cv - r * 11;
      sbase[i] = (const char*)(Vg + (size_t)r * SEQ) + (cc >= 8 ? 112 : cc * 16);
      sstride[i] = 2;                        // V tile advances kbase*2 bytes
    } else {
      sbase[i] = Kg;
      sstride[i] = 192;
    }
  }
  const int dbase = 22528 + tid * 16;        // Ps bytes + lane-linear chunks

  // ---- prologue: issue DMA for tile 0 into buf0
#pragma unroll
  for (int i = 0; i < 7; ++i)
    async16(ldsb + dbase + i * 4096, sbase[i]);

  f32x4 o_[2][5];
#pragma unroll
  for (int mi = 0; mi < 2; ++mi)
#pragma unroll
    for (int n = 0; n < 5; ++n) o_[mi][n] = (f32x4){0.f, 0.f, 0.f, 0.f};
  float l_part[2] = {0.f, 0.f};

  const int NT = SEQ / 64;
  for (int kt = 0; kt < NT; ++kt) {
    const int cur = kt & 1;
    // ---- issue DMA for tile t+1 into buf^1 (clamped on last iter)
    {
      const size_t kn = (size_t)(((kt + 1 < NT) ? kt + 1 : kt) * 64);
      const int db = dbase + (cur ^ 1) * 28672;
#pragma unroll
      for (int i = 0; i < 7; ++i)
        async16(ldsb + db + i * 4096, sbase[i] + kn * sstride[i]);
    }
    // ---- wait own tile-t DMAs (t+1's 7 stay in flight), publish via barrier
    asm volatile("s_waitcnt vmcnt(7)" ::: "memory");
    __builtin_amdgcn_s_barrier();
    __builtin_amdgcn_sched_barrier(0);

    ushort* Ks = lds + 11264 + cur * 14336;
    ushort* Vt = Ks + 6656;

    // ---- S^T = K Q^T (log2-scaled): rows=key, col=q
    f32x4 st[2][4];
#pragma unroll
    for (int mi = 0; mi < 2; ++mi)
#pragma unroll
      for (int j = 0; j < 4; ++j) st[mi][j] = (f32x4){0.f, 0.f, 0.f, 0.f};
#pragma unroll
    for (int j = 0; j < 4; ++j)
#pragma unroll
      for (int c = 0; c < 3; ++c) {
        bf16x8 kf = *(const bf16x8*)&Ks[(j * 16 + m15) * LKS + c * 32 + g * 8];
        st[0][j] = __builtin_amdgcn_mfma_f32_16x16x32_bf16(kf, qf[0][c], st[0][j], 0, 0, 0);
        st[1][j] = __builtin_amdgcn_mfma_f32_16x16x32_bf16(kf, qf[1][c], st[1][j], 0, 0, 0);
      }
    // ---- p = exp2(s); accumulate l per-lane; pack & store P^T -> Ps[q][key]
#pragma unroll
    for (int mi = 0; mi < 2; ++mi) {
      float ls = 0.f;
#pragma unroll
      for (int j = 0; j < 4; ++j) {
        float p0 = __builtin_amdgcn_exp2f(st[mi][j][0]);
        float p1 = __builtin_amdgcn_exp2f(st[mi][j][1]);
        float p2 = __builtin_amdgcn_exp2f(st[mi][j][2]);
        float p3 = __builtin_amdgcn_exp2f(st[mi][j][3]);
        ls += (p0 + p1) + (p2 + p3);
        uint2 pw;
        pw.x = pk_bf16(p0, p1);
        pw.y = pk_bf16(p2, p3);
        *(uint2*)&Ps[(w * 32 + mi * 16 + m15) * LPS + j * 16 + g * 4] = pw;
      }
      l_part[mi] += ls;
    }
    // Ps rows are wave-private; order LDS writes before cross-lane reads.
    asm volatile("s_waitcnt lgkmcnt(0)" ::: "memory");
    // ---- O += P V
#pragma unroll
    for (int kc = 0; kc < 2; ++kc) {
      bf16x8 pf0 = *(const bf16x8*)&Ps[(w * 32 + m15) * LPS + kc * 32 + g * 8];
      bf16x8 pf1 = *(const bf16x8*)&Ps[(w * 32 + 16 + m15) * LPS + kc * 32 + g * 8];
#pragma unroll
      for (int n = 0; n < 5; ++n) {
        bf16x8 vf = *(const bf16x8*)&Vt[(n * 16 + m15) * LVS + kc * 32 + g * 8];
        o_[0][n] = __builtin_amdgcn_mfma_f32_16x16x32_bf16(pf0, vf, o_[0][n], 0, 0, 0);
        o_[1][n] = __builtin_amdgcn_mfma_f32_16x16x32_bf16(pf1, vf, o_[1][n], 0, 0, 0);
      }
    }
    // ---- all waves done reading buf[cur] before next iter's DMA overwrites it
    __builtin_amdgcn_s_barrier();
    __builtin_amdgcn_sched_barrier(0);
  }
  // ---- l: reduce over g-groups; redistribute to row-owners; normalize; split
  float linv[2][4];
#pragma unroll
  for (int mi = 0; mi < 2; ++mi) {
    float t = l_part[mi];
    t += __shfl_xor(t, 16);
    t += __shfl_xor(t, 32);   // every lane: full l for q = w*32+mi*16+m15
#pragma unroll
    for (int r = 0; r < 4; ++r)
      linv[mi][r] = 1.f / __shfl(t, g * 4 + r);   // l for q-row g*4+r
  }
#pragma unroll
  for (int mi = 0; mi < 2; ++mi)
#pragma unroll
    for (int r = 0; r < 4; ++r) {
      int grow = q0 + w * 32 + mi * 16 + g * 4 + r;
      size_t base = (size_t)grow * HIDDEN + h * HD + m15;
#pragma unroll
      for (int n = 0; n < 5; ++n) {
        float x = o_[mi][n][r] * linv[mi][r];
        ushort hi = f2bf(x);
        ao_hi[base + n * 16] = hi;
        ao_lo[base + n * 16] = f2bf(x - bf2f(hi));
      }
    }
}

extern "C" void kernel_launch(void* const* d_in, const int* in_sizes, int n_in,
                              void* d_out, int out_size, void* d_ws, size_t ws_size,
                              hipStream_t stream) {
  const float* x      = (const float*)d_in[0];
  const float* cosb   = (const float*)d_in[1];
  const float* sinb   = (const float*)d_in[2];
  const float* w_qkv  = (const float*)d_in[3];
  const float* b_qkv  = (const float*)d_in[4];
  const float* w_proj = (const float*)d_in[5];
  const float* b_proj = (const float*)d_in[6];
  float* out = (float*)d_out;

  // workspace layout (aliased; all kernels strictly ordered on `stream`):
  char* ws = (char*)d_ws;
  float*  qkv   = (float*)ws;                    // 60 MB; dead after v_trans
  ushort* ao_hi = (ushort*)(ws + 42467328);      // 10,485,760 (over dead qkv)
  ushort* ao_lo = (ushort*)(ws + 52953088);      // 10,485,760
  size_t o = 62914560;
  ushort* xhi = (ushort*)(ws + o);               // 10.5 MB (hi only; no lo needed)
  ushort* Qb  = (ushort*)(ws + o);               // alias x-region after gemm1
  o += 20971520;
  ushort* wqT_h = (ushort*)(ws + o);             // 9.83 MB (hi only)
  ushort* Kb    = (ushort*)(ws + o);             // alias wqT after gemm1
  o += 19660800;
  ushort* VbT   = (ushort*)(ws + o); o += 10485760;   // 10.5 MB
  ushort* wpT_h = (ushort*)(ws + o); o += 3276800;
  ushort* wpT_l = (ushort*)(ws + o);             // total ~120.6 MB

  // 1) casts / splits
  split_rows<<<SEQ * HIDDEN / 1024, 256, 0, stream>>>(x, xhi, nullptr, SEQ * HIDDEN);
  split_T<<<dim3(QKV_N / 32, HIDDEN / 32), 256, 0, stream>>>(w_qkv, wqT_h, nullptr, HIDDEN, QKV_N);
  split_T<<<dim3(HIDDEN / 32, HIDDEN / 32), 256, 0, stream>>>(w_proj, wpT_h, wpT_l, HIDDEN, HIDDEN);
  // 2) qkv = x @ w_qkv + b_qkv   (XCD-swizzled 1D grid: 30x32=960 blocks)
  gemm_bt_bf16<<<(QKV_N / 128) * (SEQ / 128), 256, 0, stream>>>(
      xhi, wqT_h, b_qkv, qkv, SEQ, QKV_N, HIDDEN);
  // 3) rotary -> Qb/Kb; V transpose -> VbT  (qkv dead afterwards)
  rotary_qk<<<SEQ * NH * 48 / 256, 256, 0, stream>>>(qkv, cosb, sinb, Qb, Kb);
  v_trans<<<dim3(SEQ / 64, NH), 256, 0, stream>>>(qkv, VbT);
  // 4) attention + fused normalize/split -> ao_hi/ao_lo (XCD-swizzled 1D grid)
  attn_mfma<<<(SEQ / 128) * NH, 256, 0, stream>>>(Qb, Kb, VbT, ao_hi, ao_lo);
  // 5) out = attn @ w_proj + b_proj  (XCD-swizzled 1D grid: 10x32=320 blocks)
  gemm_bt_split<<<(HIDDEN / 128) * (SEQ / 128), 256, 0, stream>>>(
      ao_hi, ao_lo, wpT_h, wpT_l, b_proj, out, SEQ, HIDDEN, HIDDEN);
}

// Round 11
// 340.100 us; speedup vs baseline: 1.0657x; 1.0189x over previous
//
#include <hip/hip_runtime.h>
#include <hip/hip_bf16.h>

#define SEQ 4096
#define HIDDEN 1280
#define NH 16
#define HD 80
#define QKV_N 3840
#define INV_SCALE 0.11180339887498949f
#define LOG2E 1.4426950408889634f

typedef __attribute__((ext_vector_type(8))) short bf16x8;
typedef __attribute__((ext_vector_type(4))) float f32x4;

__device__ __forceinline__ ushort f2bf(float f) {
  union { float f; unsigned u; } v; v.f = f;
  unsigned u = v.u;
  u += 0x7fff + ((u >> 16) & 1);   // RTNE
  return (ushort)(u >> 16);
}
__device__ __forceinline__ float bf2f(ushort h) {
  union { unsigned u; float f; } v; v.u = ((unsigned)h) << 16;
  return v.f;
}
__device__ __forceinline__ unsigned pk_bf16(float a, float b) {
  union { __hip_bfloat162 h; unsigned u; } v;
  v.h = __float22bfloat162_rn(make_float2(a, b));
  return v.u;
}
// async global->LDS, 16B per lane. LDS side must be base + lane*16 contiguous.
__device__ __forceinline__ void async16(void* lds, const void* g) {
  __builtin_amdgcn_global_load_lds(
      (const __attribute__((address_space(1))) unsigned*)g,
      (__attribute__((address_space(3))) unsigned*)(unsigned)(size_t)lds,
      16, 0, 0);
}

// -------- split fp32 -> bf16 hi (+optional lo), elementwise --------
__global__ __launch_bounds__(256)
void split_rows(const float* __restrict__ A, ushort* __restrict__ hi,
                ushort* __restrict__ lo, int n) {
  int i = (blockIdx.x * 256 + threadIdx.x) * 4;
  if (i >= n) return;
  float4 v = *(const float4*)&A[i];
  ushort h[4], l[4];
  float x[4] = {v.x, v.y, v.z, v.w};
#pragma unroll
  for (int t = 0; t < 4; ++t) {
    h[t] = f2bf(x[t]);
    l[t] = f2bf(x[t] - bf2f(h[t]));
  }
  *(ushort4*)&hi[i] = *(ushort4*)h;
  if (lo) *(ushort4*)&lo[i] = *(ushort4*)l;
}

// ---- split + transpose: W[K][N] -> hiT (+optional loT) [N][K] ----
__global__ __launch_bounds__(256)
void split_T(const float* __restrict__ W, ushort* __restrict__ hiT,
             ushort* __restrict__ loT, int K, int N) {
  __shared__ float T[32][33];
  const int k0 = blockIdx.y * 32, n0 = blockIdx.x * 32;
  for (int e = threadIdx.x; e < 1024; e += 256) {
    int r = e >> 5, c = e & 31;
    T[r][c] = W[(size_t)(k0 + r) * N + n0 + c];
  }
  __syncthreads();
  for (int e = threadIdx.x; e < 1024; e += 256) {
    int r = e >> 5, c = e & 31;        // r: n-index, c: k-index
    float x = T[c][r];
    ushort h = f2bf(x);
    size_t idx = (size_t)(n0 + r) * K + k0 + c;
    hiT[idx] = h;
    if (loT) loT[idx] = f2bf(x - bf2f(h));
  }
}

// ------- pure-bf16 GEMM: Cb[M,N] = bf16(A[M,K] @ B^T[N,K] + bias) -------
// 128x128 tile, BK=64, 4 waves, DMA double-buffer + counted vmcnt + XCD swizzle.
// R15: output is bf16 (ushort) -- every consumer of qkv casts to bf16 anyway,
// so write it rounded once here and halve the 60MB qkv round-trip.
__global__ __launch_bounds__(256, 2)
void gemm_bt_bf16(const ushort* __restrict__ Ab, const ushort* __restrict__ Bb,
                  const float* __restrict__ bias, ushort* __restrict__ Cb,
                  int M, int N, int K) {
  __shared__ __align__(16) ushort lds[32768];   // 2 bufs x (A0|A1|B0|B1, 8KB each)
  const int tid = threadIdx.x, lane = tid & 63, w = tid >> 6;
  const int m15 = lane & 15, g = lane >> 4;
  const int id = blockIdx.x;
  const int swz = (id & 7) * ((int)gridDim.x >> 3) + (id >> 3);
  const int nbx = N >> 7;
  const int m0 = (swz / nbx) * 128, n0 = (swz % nbx) * 128;
  const int wm = (w & 1) * 64, wn = (w >> 1) * 64;

  const ushort* stage_base =
      (w < 2) ? Ab + (size_t)m0 * K + (w & 1) * 32
              : Bb + (size_t)n0 * K + (w & 1) * 32;
  char* ldsb = (char*)lds;

  // bias first: oldest VMEM ops, drained by any later vmcnt
  float bv[4];
#pragma unroll
  for (int ni = 0; ni < 4; ++ni) bv[ni] = bias[n0 + wn + ni * 16 + m15];

  f32x4 acc[4][4];
#pragma unroll
  for (int i = 0; i < 4; ++i)
#pragma unroll
    for (int j = 0; j < 4; ++j) acc[i][j] = (f32x4){0.f, 0.f, 0.f, 0.f};

  const int NK = K >> 6;
  // prologue: tile 0 -> buf0
#pragma unroll
  for (int i = 0; i < 8; ++i) {
    int o = i * 1024 + lane * 16;      // byte offset within 8KB region
    int row = o >> 6, colb = o & 63;   // 64 B per row (32 bf16)
    async16(ldsb + w * 8192 + o, (const char*)(stage_base + (size_t)row * K) + colb);
  }
  for (int it = 0; it < NK; ++it) {
    const int cur = it & 1;
    const int kn = ((it + 1 < NK) ? it + 1 : it) * 64;
#pragma unroll
    for (int i = 0; i < 8; ++i) {
      int o = i * 1024 + lane * 16;
      int row = o >> 6, colb = o & 63;
      async16(ldsb + (cur ^ 1) * 32768 + w * 8192 + o,
              (const char*)(stage_base + (size_t)row * K + kn) + colb);
    }
    asm volatile("s_waitcnt vmcnt(8)" ::: "memory");
    __builtin_amdgcn_s_barrier();
    __builtin_amdgcn_sched_barrier(0);

    const ushort* L = lds + cur * 16384;
    bf16x8 ah[4][2], bh[4][2];
#pragma unroll
    for (int t = 0; t < 4; ++t) {
      ah[t][0] = *(const bf16x8*)&L[(wm + t * 16 + m15) * 32 + g * 8];
      ah[t][1] = *(const bf16x8*)&L[4096 + (wm + t * 16 + m15) * 32 + g * 8];
      bh[t][0] = *(const bf16x8*)&L[8192 + (wn + t * 16 + m15) * 32 + g * 8];
      bh[t][1] = *(const bf16x8*)&L[12288 + (wn + t * 16 + m15) * 32 + g * 8];
    }
#pragma unroll
    for (int mi = 0; mi < 4; ++mi)
#pragma unroll
      for (int ni = 0; ni < 4; ++ni) {
        acc[mi][ni] = __builtin_amdgcn_mfma_f32_16x16x32_bf16(ah[mi][0], bh[ni][0], acc[mi][ni], 0, 0, 0);
        acc[mi][ni] = __builtin_amdgcn_mfma_f32_16x16x32_bf16(ah[mi][1], bh[ni][1], acc[mi][ni], 0, 0, 0);
      }
    __builtin_amdgcn_s_barrier();
    __builtin_amdgcn_sched_barrier(0);
  }
#pragma unroll
  for (int mi = 0; mi < 4; ++mi)
#pragma unroll
    for (int ni = 0; ni < 4; ++ni) {
      int col = n0 + wn + ni * 16 + m15;
#pragma unroll
      for (int r = 0; r < 4; ++r)
        Cb[(size_t)(m0 + wm + mi * 16 + g * 4 + r) * N + col] =
            f2bf(acc[mi][ni][r] + bv[ni]);
    }
}

// ------- split-bf16 GEMM: C[M,N] = (Ah+Al)[M,K] @ (Bh+Bl)^T[N,K] + bias -------
__global__ __launch_bounds__(256, 2)
void gemm_bt_split(const ushort* __restrict__ Ah, const ushort* __restrict__ Al,
                   const ushort* __restrict__ Bh, const ushort* __restrict__ Bl,
                   const float* __restrict__ bias, float* __restrict__ C,
                   int M, int N, int K) {
  __shared__ __align__(16) ushort lds[32768];   // 2 bufs x (Ah|Al|Bh|Bl, 8KB each)
  const int tid = threadIdx.x, lane = tid & 63, w = tid >> 6;
  const int m15 = lane & 15, g = lane >> 4;
  const int id = blockIdx.x;
  const int swz = (id & 7) * ((int)gridDim.x >> 3) + (id >> 3);
  const int nbx = N >> 7;
  const int m0 = (swz / nbx) * 128, n0 = (swz % nbx) * 128;
  const int wm = (w & 1) * 64, wn = (w >> 1) * 64;

  const ushort* stage_base =
      (w == 0) ? Ah + (size_t)m0 * K :
      (w == 1) ? Al + (size_t)m0 * K :
      (w == 2) ? Bh + (size_t)n0 * K : Bl + (size_t)n0 * K;
  char* ldsb = (char*)lds;

  float bv[4];
#pragma unroll
  for (int ni = 0; ni < 4; ++ni) bv[ni] = bias[n0 + wn + ni * 16 + m15];

  f32x4 acc[4][4];
#pragma unroll
  for (int i = 0; i < 4; ++i)
#pragma unroll
    for (int j = 0; j < 4; ++j) acc[i][j] = (f32x4){0.f, 0.f, 0.f, 0.f};

  const int NK = K >> 5;
#pragma unroll
  for (int i = 0; i < 8; ++i) {
    int o = i * 1024 + lane * 16;
    int row = o >> 6, colb = o & 63;
    async16(ldsb + w * 8192 + o, (const char*)(stage_base + (size_t)row * K) + colb);
  }
  for (int it = 0; it < NK; ++it) {
    const int cur = it & 1;
    const int kn = ((it + 1 < NK) ? it + 1 : it) * 32;
#pragma unroll
    for (int i = 0; i < 8; ++i) {
      int o = i * 1024 + lane * 16;
      int row = o >> 6, colb = o & 63;
      async16(ldsb + (cur ^ 1) * 32768 + w * 8192 + o,
              (const char*)(stage_base + (size_t)row * K + kn) + colb);
    }
    asm volatile("s_waitcnt vmcnt(8)" ::: "memory");
    __builtin_amdgcn_s_barrier();
    __builtin_amdgcn_sched_barrier(0);

    const ushort* L = lds + cur * 16384;
    bf16x8 ah[4], al[4], bh[4], bl[4];
#pragma unroll
    for (int t = 0; t < 4; ++t) {
      ah[t] = *(const bf16x8*)&L[(wm + t * 16 + m15) * 32 + g * 8];
      al[t] = *(const bf16x8*)&L[4096 + (wm + t * 16 + m15) * 32 + g * 8];
      bh[t] = *(const bf16x8*)&L[8192 + (wn + t * 16 + m15) * 32 + g * 8];
      bl[t] = *(const bf16x8*)&L[12288 + (wn + t * 16 + m15) * 32 + g * 8];
    }
#pragma unroll
    for (int mi = 0; mi < 4; ++mi)
#pragma unroll
      for (int ni = 0; ni < 4; ++ni) {
        acc[mi][ni] = __builtin_amdgcn_mfma_f32_16x16x32_bf16(ah[mi], bh[ni], acc[mi][ni], 0, 0, 0);
        acc[mi][ni] = __builtin_amdgcn_mfma_f32_16x16x32_bf16(ah[mi], bl[ni], acc[mi][ni], 0, 0, 0);
        acc[mi][ni] = __builtin_amdgcn_mfma_f32_16x16x32_bf16(al[mi], bh[ni], acc[mi][ni], 0, 0, 0);
      }
    __builtin_amdgcn_s_barrier();
    __builtin_amdgcn_sched_barrier(0);
  }
#pragma unroll
  for (int mi = 0; mi < 4; ++mi)
#pragma unroll
    for (int ni = 0; ni < 4; ++ni) {
      int col = n0 + wn + ni * 16 + m15;
#pragma unroll
      for (int r = 0; r < 4; ++r)
        C[(size_t)(m0 + wm + mi * 16 + g * 4 + r) * N + col] = acc[mi][ni][r] + bv[ni];
    }
}

// ------------- rotary + cast: Qb/Kb [h][s][96] (zero-padded); bf16 qkv in ----
__global__ __launch_bounds__(256)
void rotary_qk(const ushort* __restrict__ qkvb, const float* __restrict__ cosb,
               const float* __restrict__ sinb, ushort* __restrict__ Qb,
               ushort* __restrict__ Kb) {
  int id = blockIdx.x * 256 + threadIdx.x;
  int j = id % 48;
  int h = (id / 48) % NH;
  int s = id / (48 * NH);
  size_t qrow = (size_t)((h << 12) + s) * 96;
  if (j < 40) {
    size_t base = (size_t)s * QKV_N + h * HD;
    float c1 = cosb[s * HD + j],      s1 = sinb[s * HD + j];
    float c2 = cosb[s * HD + j + 40], s2 = sinb[s * HD + j + 40];
    const float QS = INV_SCALE * LOG2E;
    float q1 = bf2f(qkvb[base + j]), q2 = bf2f(qkvb[base + j + 40]);
    Qb[qrow + j]      = f2bf((q1 * c1 - q2 * s1) * QS);
    Qb[qrow + j + 40] = f2bf((q2 * c2 + q1 * s2) * QS);
    float k1 = bf2f(qkvb[base + HIDDEN + j]), k2 = bf2f(qkvb[base + HIDDEN + j + 40]);
    Kb[qrow + j]      = f2bf(k1 * c1 - k2 * s1);
    Kb[qrow + j + 40] = f2bf(k2 * c2 + k1 * s2);
  } else {
    int d = 80 + (j - 40) * 2;
    Qb[qrow + d] = 0; Qb[qrow + d + 1] = 0;
    Kb[qrow + d] = 0; Kb[qrow + d + 1] = 0;
  }
}

// ------- V transpose: qkvb v-section (bf16) -> VbT[h][80][4096] bf16 -------
__global__ __launch_bounds__(256)
void v_trans(const ushort* __restrict__ qkvb, ushort* __restrict__ VbT) {
  __shared__ ushort T[64][81];   // odd ushort stride: read phase conflict-free
  const int h = blockIdx.y, s0 = blockIdx.x * 64;
  for (int e = threadIdx.x; e < 5120; e += 256) {
    int r = e / 80, d = e % 80;
    T[r][d] = qkvb[(size_t)(s0 + r) * QKV_N + 2 * HIDDEN + h * HD + d];
  }
  __syncthreads();
  for (int e = threadIdx.x; e < 2560; e += 256) {
    int d = e >> 5, rp = (e & 31) * 2;
    ushort2 p;
    p.x = T[rp][d];
    p.y = T[rp + 1][d];
    *(ushort2*)&VbT[(size_t)h * 80 * SEQ + (size_t)d * SEQ + s0 + rp] = p;
  }
}

// ---- flash attention, bf16 MFMA, fixed-max softmax, fused normalize ----
// grid 512 x 256 threads (4 waves x 32 q-rows). VERIFIED R14 BODY (127.5us):
// XCD swizzle (FETCH 96->17.5MB), no setprio, no V-hoist.
// Pipeline per iter (R8): issue 7 DMA chunks for t+1 -> s_waitcnt vmcnt(7)
// -> s_barrier -> compute t -> s_barrier. LDS 79,872 B -> 2 blocks/CU.
#define LPS 88    // Ps row stride (ushort)
#define LKS 104   // Ks row stride (ushort): 208 B = 13 chunks; 52 dw == 20 mod 32
#define LVS 88    // Vt row stride (ushort): 176 B = 11 chunks; 44 dw == 12 mod 32
__global__ __launch_bounds__(256, 2)
void attn_mfma(const ushort* __restrict__ Qb, const ushort* __restrict__ Kb,
               const ushort* __restrict__ VbT, ushort* __restrict__ ao_hi,
               ushort* __restrict__ ao_lo) {
  // [0,11264) ushorts: Ps[128][LPS] (22528 B)
  // buf b at byte 22528 + b*28672: Ks 64x[LKS] (13312 B) | Vt 80x[LVS] (14080 B)
  //   | pad 1280 B.  Total 22528 + 2*28672 = 79872 B.
  __shared__ __align__(16) ushort lds[39936];
  ushort* Ps = lds;
  char* ldsb = (char*)lds;

  const int tid = threadIdx.x, lane = tid & 63, w = tid >> 6;
  const int m15 = lane & 15, g = lane >> 4;
  const int idp = blockIdx.x;
  const int logical = (idp & 7) * 64 + (idp >> 3);   // XCD-contiguous
  const int h = logical >> 5, q0 = (logical & 31) * 128;
  const size_t hq = (size_t)h * SEQ * 96;
  const ushort* Qg = Qb + hq + (size_t)q0 * 96;
  const char* Kg = (const char*)(Kb + hq);
  const ushort* Vg = VbT + (size_t)h * 80 * SEQ;

  // ---- Q fragments straight from global (one-time, 6x16B per lane)
  bf16x8 qf[2][3];
#pragma unroll
  for (int mi = 0; mi < 2; ++mi)
#pragma unroll
    for (int c = 0; c < 3; ++c)
      qf[mi][c] = *(const bf16x8*)&Qg[(w * 32 + mi * 16 + m15) * 96 + c * 32 + g * 8];

  // ---- DMA source map: 1792 16B chunks/tile (K 832 | V 880 | pad 80), 7/thread.
  const char* sbase[7];
  int sstride[7];
#pragma unroll
  for (int i = 0; i < 7; ++i) {
    int c = tid + i * 256;
    if (c < 832) {
      int r = c / 13, cc = c - r * 13;
      sbase[i] = Kg + r * 192 + (cc == 12 ? 176 : cc * 16);
      sstride[i] = 192;                      // K tile advances kbase*192 bytes
    } else if (c < 1712) {
      int cv = c - 832;
      int r = cv / 11, cc = cv - r * 11;
      sbase[i] = (const char*)(Vg + (size_t)r * SEQ) + (cc >= 8 ? 112 : cc * 16);
      sstride[i] = 2;                        // V tile advances kbase*2 bytes
    } else {
      sbase[i] = Kg;
      sstride[i] = 192;
    }
  }
  const int dbase = 22528 + tid * 16;        // Ps bytes + lane-linear chunks

  // ---- prologue: issue DMA for tile 0 into buf0
#pragma unroll
  for (int i = 0; i < 7; ++i)
    async16(ldsb + dbase + i * 4096, sbase[i]);

  f32x4 o_[2][5];
#pragma unroll
  for (int mi = 0; mi < 2; ++mi)
#pragma unroll
    for (int n = 0; n < 5; ++n) o_[mi][n] = (f32x4){0.f, 0.f, 0.f, 0.f};
  float l_part[2] = {0.f, 0.f};

  const int NT = SEQ / 64;
  for (int kt = 0; kt < NT; ++kt) {
    const int cur = kt & 1;
    // ---- issue DMA for tile t+1 into buf^1 (clamped on last iter)
    {
      const size_t kn = (size_t)(((kt + 1 < NT) ? kt + 1 : kt) * 64);
      const int db = dbase + (cur ^ 1) * 28672;
#pragma unroll
      for (int i = 0; i < 7; ++i)
        async16(ldsb + db + i * 4096, sbase[i] + kn * sstride[i]);
    }
    // ---- wait own tile-t DMAs (t+1's 7 stay in flight), publish via barrier
    asm volatile("s_waitcnt vmcnt(7)" ::: "memory");
    __builtin_amdgcn_s_barrier();
    __builtin_amdgcn_sched_barrier(0);

    ushort* Ks = lds + 11264 + cur * 14336;
    ushort* Vt = Ks + 6656;

    // ---- S^T = K Q^T (log2-scaled): rows=key, col=q
    f32x4 st[2][4];
#pragma unroll
    for (int mi = 0; mi < 2; ++mi)
#pragma unroll
      for (int j = 0; j < 4; ++j) st[mi][j] = (f32x4){0.f, 0.f, 0.f, 0.f};
#pragma unroll
    for (int j = 0; j < 4; ++j)
#pragma unroll
      for (int c = 0; c < 3; ++c) {
        bf16x8 kf = *(const bf16x8*)&Ks[(j * 16 + m15) * LKS + c * 32 + g * 8];
        st[0][j] = __builtin_amdgcn_mfma_f32_16x16x32_bf16(kf, qf[0][c], st[0][j], 0, 0, 0);
        st[1][j] = __builtin_amdgcn_mfma_f32_16x16x32_bf16(kf, qf[1][c], st[1][j], 0, 0, 0);
      }
    // ---- p = exp2(s); accumulate l per-lane; pack & store P^T -> Ps[q][key]
#pragma unroll
    for (int mi = 0; mi < 2; ++mi) {
      float ls = 0.f;
#pragma unroll
      for (int j = 0; j < 4; ++j) {
        float p0 = __builtin_amdgcn_exp2f(st[mi][j][0]);
        float p1 = __builtin_amdgcn_exp2f(st[mi][j][1]);
        float p2 = __builtin_amdgcn_exp2f(st[mi][j][2]);
        float p3 = __builtin_amdgcn_exp2f(st[mi][j][3]);
        ls += (p0 + p1) + (p2 + p3);
        uint2 pw;
        pw.x = pk_bf16(p0, p1);
        pw.y = pk_bf16(p2, p3);
        *(uint2*)&Ps[(w * 32 + mi * 16 + m15) * LPS + j * 16 + g * 4] = pw;
      }
      l_part[mi] += ls;
    }
    // Ps rows are wave-private; order LDS writes before cross-lane reads.
    asm volatile("s_waitcnt lgkmcnt(0)" ::: "memory");
    // ---- O += P V
#pragma unroll
    for (int kc = 0; kc < 2; ++kc) {
      bf16x8 pf0 = *(const bf16x8*)&Ps[(w * 32 + m15) * LPS + kc * 32 + g * 8];
      bf16x8 pf1 = *(const bf16x8*)&Ps[(w * 32 + 16 + m15) * LPS + kc * 32 + g * 8];
#pragma unroll
      for (int n = 0; n < 5; ++n) {
        bf16x8 vf = *(const bf16x8*)&Vt[(n * 16 + m15) * LVS + kc * 32 + g * 8];
        o_[0][n] = __builtin_amdgcn_mfma_f32_16x16x32_bf16(pf0, vf, o_[0][n], 0, 0, 0);
        o_[1][n] = __builtin_amdgcn_mfma_f32_16x16x32_bf16(pf1, vf, o_[1][n], 0, 0, 0);
      }
    }
    // ---- all waves done reading buf[cur] before next iter's DMA overwrites it
    __builtin_amdgcn_s_barrier();
    __builtin_amdgcn_sched_barrier(0);
  }
  // ---- l: reduce over g-groups; redistribute to row-owners; normalize; split
  float linv[2][4];
#pragma unroll
  for (int mi = 0; mi < 2; ++mi) {
    float t = l_part[mi];
    t += __shfl_xor(t, 16);
    t += __shfl_xor(t, 32);   // every lane: full l for q = w*32+mi*16+m15
#pragma unroll
    for (int r = 0; r < 4; ++r)
      linv[mi][r] = 1.f / __shfl(t, g * 4 + r);   // l for q-row g*4+r
  }
#pragma unroll
  for (int mi = 0; mi < 2; ++mi)
#pragma unroll
    for (int r = 0; r < 4; ++r) {
      int grow = q0 + w * 32 + mi * 16 + g * 4 + r;
      size_t base = (size_t)grow * HIDDEN + h * HD + m15;
#pragma unroll
      for (int n = 0; n < 5; ++n) {
        float x = o_[mi][n][r] * linv[mi][r];
        ushort hi = f2bf(x);
        ao_hi[base + n * 16] = hi;
        ao_lo[base + n * 16] = f2bf(x - bf2f(hi));
      }
    }
}

extern "C" void kernel_launch(void* const* d_in, const int* in_sizes, int n_in,
                              void* d_out, int out_size, void* d_ws, size_t ws_size,
                              hipStream_t stream) {
  const float* x      = (const float*)d_in[0];
  const float* cosb   = (const float*)d_in[1];
  const float* sinb   = (const float*)d_in[2];
  const float* w_qkv  = (const float*)d_in[3];
  const float* b_qkv  = (const float*)d_in[4];
  const float* w_proj = (const float*)d_in[5];
  const float* b_proj = (const float*)d_in[6];
  float* out = (float*)d_out;

  // workspace layout (aliased; all kernels strictly ordered on `stream`):
  char* ws = (char*)d_ws;
  ushort* qkvb  = (ushort*)ws;                   // bf16 qkv, 30 MB; dead after v_trans
  ushort* ao_hi = (ushort*)(ws + 42467328);      // 10,485,760 (over dead qkv region)
  ushort* ao_lo = (ushort*)(ws + 52953088);      // 10,485,760
  size_t o = 62914560;
  ushort* xhi = (ushort*)(ws + o);               // 10.5 MB (hi only; no lo needed)
  ushort* Qb  = (ushort*)(ws + o);               // alias x-region after gemm1
  o += 20971520;
  ushort* wqT_h = (ushort*)(ws + o);             // 9.83 MB (hi only)
  ushort* Kb    = (ushort*)(ws + o);             // alias wqT after gemm1
  o += 19660800;
  ushort* VbT   = (ushort*)(ws + o); o += 10485760;   // 10.5 MB
  ushort* wpT_h = (ushort*)(ws + o); o += 3276800;
  ushort* wpT_l = (ushort*)(ws + o);             // total ~120.6 MB

  // 1) casts / splits
  split_rows<<<SEQ * HIDDEN / 1024, 256, 0, stream>>>(x, xhi, nullptr, SEQ * HIDDEN);
  split_T<<<dim3(QKV_N / 32, HIDDEN / 32), 256, 0, stream>>>(w_qkv, wqT_h, nullptr, HIDDEN, QKV_N);
  split_T<<<dim3(HIDDEN / 32, HIDDEN / 32), 256, 0, stream>>>(w_proj, wpT_h, wpT_l, HIDDEN, HIDDEN);
  // 2) qkvb = bf16(x @ w_qkv + b_qkv)   (XCD-swizzled 1D grid: 30x32=960 blocks)
  gemm_bt_bf16<<<(QKV_N / 128) * (SEQ / 128), 256, 0, stream>>>(
      xhi, wqT_h, b_qkv, qkvb, SEQ, QKV_N, HIDDEN);
  // 3) rotary -> Qb/Kb; V transpose -> VbT  (qkvb dead afterwards)
  rotary_qk<<<SEQ * NH * 48 / 256, 256, 0, stream>>>(qkvb, cosb, sinb, Qb, Kb);
  v_trans<<<dim3(SEQ / 64, NH), 256, 0, stream>>>(qkvb, VbT);
  // 4) attention + fused normalize/split -> ao_hi/ao_lo (XCD-swizzled 1D grid)
  attn_mfma<<<(SEQ / 128) * NH, 256, 0, stream>>>(Qb, Kb, VbT, ao_hi, ao_lo);
  // 5) out = attn @ w_proj + b_proj  (XCD-swizzled 1D grid: 10x32=320 blocks)
  gemm_bt_split<<<(HIDDEN / 128) * (SEQ / 128), 256, 0, stream>>>(
      ao_hi, ao_lo, wpT_h, wpT_l, b_proj, out, SEQ, HIDDEN, HIDDEN);
}

// Round 15
// 309.450 us; speedup vs baseline: 1.1713x; 1.0990x over previous
//
#include <hip/hip_runtime.h>
#include <hip/hip_bf16.h>

#define SEQ 4096
#define HIDDEN 1280
#define NH 16
#define HD 80
#define QKV_N 3840
#define INV_SCALE 0.11180339887498949f
#define LOG2E 1.4426950408889634f

typedef __attribute__((ext_vector_type(8))) short bf16x8;
typedef __attribute__((ext_vector_type(8))) _Float16 f16x8;
typedef __attribute__((ext_vector_type(4))) float f32x4;

__device__ __forceinline__ ushort f2bf(float f) {
  union { float f; unsigned u; } v; v.f = f;
  unsigned u = v.u;
  u += 0x7fff + ((u >> 16) & 1);   // RTNE
  return (ushort)(u >> 16);
}
__device__ __forceinline__ float bf2f(ushort h) {
  union { unsigned u; float f; } v; v.u = ((unsigned)h) << 16;
  return v.f;
}
__device__ __forceinline__ ushort f2h(float f) {
  union { _Float16 h; ushort u; } v; v.h = (_Float16)f;   // RTNE cvt
  return v.u;
}
__device__ __forceinline__ unsigned pk_bf16(float a, float b) {
  union { __hip_bfloat162 h; unsigned u; } v;
  v.h = __float22bfloat162_rn(make_float2(a, b));
  return v.u;
}
// async global->LDS, 16B per lane. LDS side must be base + lane*16 contiguous.
__device__ __forceinline__ void async16(void* lds, const void* g) {
  __builtin_amdgcn_global_load_lds(
      (const __attribute__((address_space(1))) unsigned*)g,
      (__attribute__((address_space(3))) unsigned*)(unsigned)(size_t)lds,
      16, 0, 0);
}

// -------- cast fp32 -> bf16, elementwise --------
__global__ __launch_bounds__(256)
void split_rows(const float* __restrict__ A, ushort* __restrict__ hi, int n) {
  int i = (blockIdx.x * 256 + threadIdx.x) * 4;
  if (i >= n) return;
  float4 v = *(const float4*)&A[i];
  ushort h[4];
  float x[4] = {v.x, v.y, v.z, v.w};
#pragma unroll
  for (int t = 0; t < 4; ++t) h[t] = f2bf(x[t]);
  *(ushort4*)&hi[i] = *(ushort4*)h;
}

// ---- cast + transpose: W[K][N] -> bf16 T [N][K] ----
__global__ __launch_bounds__(256)
void split_T(const float* __restrict__ W, ushort* __restrict__ hiT, int K, int N) {
  __shared__ float T[32][33];
  const int k0 = blockIdx.y * 32, n0 = blockIdx.x * 32;
  for (int e = threadIdx.x; e < 1024; e += 256) {
    int r = e >> 5, c = e & 31;
    T[r][c] = W[(size_t)(k0 + r) * N + n0 + c];
  }
  __syncthreads();
  for (int e = threadIdx.x; e < 1024; e += 256) {
    int r = e >> 5, c = e & 31;        // r: n-index, c: k-index
    hiT[(size_t)(n0 + r) * K + k0 + c] = f2bf(T[c][r]);
  }
}

// ---- cast + transpose: W[K][N] -> fp16 T [N][K] (proj weight) ----
__global__ __launch_bounds__(256)
void cast_T_f16(const float* __restrict__ W, ushort* __restrict__ T16, int K, int N) {
  __shared__ float T[32][33];
  const int k0 = blockIdx.y * 32, n0 = blockIdx.x * 32;
  for (int e = threadIdx.x; e < 1024; e += 256) {
    int r = e >> 5, c = e & 31;
    T[r][c] = W[(size_t)(k0 + r) * N + n0 + c];
  }
  __syncthreads();
  for (int e = threadIdx.x; e < 1024; e += 256) {
    int r = e >> 5, c = e & 31;
    T16[(size_t)(n0 + r) * K + k0 + c] = f2h(T[c][r]);
  }
}

// ------- pure-bf16 GEMM: Cb[M,N] = bf16(A[M,K] @ B^T[N,K] + bias) -------
// 128x128 tile, BK=64, 4 waves, DMA double-buffer + counted vmcnt + XCD swizzle.
__global__ __launch_bounds__(256, 2)
void gemm_bt_bf16(const ushort* __restrict__ Ab, const ushort* __restrict__ Bb,
                  const float* __restrict__ bias, ushort* __restrict__ Cb,
                  int M, int N, int K) {
  __shared__ __align__(16) ushort lds[32768];   // 2 bufs x (A0|A1|B0|B1, 8KB each)
  const int tid = threadIdx.x, lane = tid & 63, w = tid >> 6;
  const int m15 = lane & 15, g = lane >> 4;
  const int id = blockIdx.x;
  const int swz = (id & 7) * ((int)gridDim.x >> 3) + (id >> 3);
  const int nbx = N >> 7;
  const int m0 = (swz / nbx) * 128, n0 = (swz % nbx) * 128;
  const int wm = (w & 1) * 64, wn = (w >> 1) * 64;

  const ushort* stage_base =
      (w < 2) ? Ab + (size_t)m0 * K + (w & 1) * 32
              : Bb + (size_t)n0 * K + (w & 1) * 32;
  char* ldsb = (char*)lds;

  // bias first: oldest VMEM ops, drained by any later vmcnt
  float bv[4];
#pragma unroll
  for (int ni = 0; ni < 4; ++ni) bv[ni] = bias[n0 + wn + ni * 16 + m15];

  f32x4 acc[4][4];
#pragma unroll
  for (int i = 0; i < 4; ++i)
#pragma unroll
    for (int j = 0; j < 4; ++j) acc[i][j] = (f32x4){0.f, 0.f, 0.f, 0.f};

  const int NK = K >> 6;
  // prologue: tile 0 -> buf0
#pragma unroll
  for (int i = 0; i < 8; ++i) {
    int o = i * 1024 + lane * 16;      // byte offset within 8KB region
    int row = o >> 6, colb = o & 63;   // 64 B per row (32 bf16)
    async16(ldsb + w * 8192 + o, (const char*)(stage_base + (size_t)row * K) + colb);
  }
  for (int it = 0; it < NK; ++it) {
    const int cur = it & 1;
    const int kn = ((it + 1 < NK) ? it + 1 : it) * 64;
#pragma unroll
    for (int i = 0; i < 8; ++i) {
      int o = i * 1024 + lane * 16;
      int row = o >> 6, colb = o & 63;
      async16(ldsb + (cur ^ 1) * 32768 + w * 8192 + o,
              (const char*)(stage_base + (size_t)row * K + kn) + colb);
    }
    asm volatile("s_waitcnt vmcnt(8)" ::: "memory");
    __builtin_amdgcn_s_barrier();
    __builtin_amdgcn_sched_barrier(0);

    const ushort* L = lds + cur * 16384;
    bf16x8 ah[4][2], bh[4][2];
#pragma unroll
    for (int t = 0; t < 4; ++t) {
      ah[t][0] = *(const bf16x8*)&L[(wm + t * 16 + m15) * 32 + g * 8];
      ah[t][1] = *(const bf16x8*)&L[4096 + (wm + t * 16 + m15) * 32 + g * 8];
      bh[t][0] = *(const bf16x8*)&L[8192 + (wn + t * 16 + m15) * 32 + g * 8];
      bh[t][1] = *(const bf16x8*)&L[12288 + (wn + t * 16 + m15) * 32 + g * 8];
    }
#pragma unroll
    for (int mi = 0; mi < 4; ++mi)
#pragma unroll
      for (int ni = 0; ni < 4; ++ni) {
        acc[mi][ni] = __builtin_amdgcn_mfma_f32_16x16x32_bf16(ah[mi][0], bh[ni][0], acc[mi][ni], 0, 0, 0);
        acc[mi][ni] = __builtin_amdgcn_mfma_f32_16x16x32_bf16(ah[mi][1], bh[ni][1], acc[mi][ni], 0, 0, 0);
      }
    __builtin_amdgcn_s_barrier();
    __builtin_amdgcn_sched_barrier(0);
  }
#pragma unroll
  for (int mi = 0; mi < 4; ++mi)
#pragma unroll
    for (int ni = 0; ni < 4; ++ni) {
      int col = n0 + wn + ni * 16 + m15;
#pragma unroll
      for (int r = 0; r < 4; ++r)
        Cb[(size_t)(m0 + wm + mi * 16 + g * 4 + r) * N + col] =
            f2bf(acc[mi][ni][r] + bv[ni]);
    }
}

// ------- pure-fp16 GEMM: C[M,N] = A[M,K] @ B^T[N,K] + bias (fp32 out) -------
// R16-R19: replaces the 3-pass split-bf16 proj GEMM. Same verified pipeline
// (BK=64, DMA dbuf, vmcnt(8), XCD swizzle); fp16 inputs give error
// ~1e-4 absolute at K=1280 -- well under threshold. 1/3 the MFMAs, half
// the iterations of the old split kernel.
__global__ __launch_bounds__(256, 2)
void gemm_bt_f16(const ushort* __restrict__ Ab, const ushort* __restrict__ Bb,
                 const float* __restrict__ bias, float* __restrict__ C,
                 int M, int N, int K) {
  __shared__ __align__(16) ushort lds[32768];   // 2 bufs x (A0|A1|B0|B1, 8KB each)
  const int tid = threadIdx.x, lane = tid & 63, w = tid >> 6;
  const int m15 = lane & 15, g = lane >> 4;
  const int id = blockIdx.x;
  const int swz = (id & 7) * ((int)gridDim.x >> 3) + (id >> 3);
  const int nbx = N >> 7;
  const int m0 = (swz / nbx) * 128, n0 = (swz % nbx) * 128;
  const int wm = (w & 1) * 64, wn = (w >> 1) * 64;

  const ushort* stage_base =
      (w < 2) ? Ab + (size_t)m0 * K + (w & 1) * 32
              : Bb + (size_t)n0 * K + (w & 1) * 32;
  char* ldsb = (char*)lds;

  float bv[4];
#pragma unroll
  for (int ni = 0; ni < 4; ++ni) bv[ni] = bias[n0 + wn + ni * 16 + m15];

  f32x4 acc[4][4];
#pragma unroll
  for (int i = 0; i < 4; ++i)
#pragma unroll
    for (int j = 0; j < 4; ++j) acc[i][j] = (f32x4){0.f, 0.f, 0.f, 0.f};

  const int NK = K >> 6;
#pragma unroll
  for (int i = 0; i < 8; ++i) {
    int o = i * 1024 + lane * 16;
    int row = o >> 6, colb = o & 63;
    async16(ldsb + w * 8192 + o, (const char*)(stage_base + (size_t)row * K) + colb);
  }
  for (int it = 0; it < NK; ++it) {
    const int cur = it & 1;
    const int kn = ((it + 1 < NK) ? it + 1 : it) * 64;
#pragma unroll
    for (int i = 0; i < 8; ++i) {
      int o = i * 1024 + lane * 16;
      int row = o >> 6, colb = o & 63;
      async16(ldsb + (cur ^ 1) * 32768 + w * 8192 + o,
              (const char*)(stage_base + (size_t)row * K + kn) + colb);
    }
    asm volatile("s_waitcnt vmcnt(8)" ::: "memory");
    __builtin_amdgcn_s_barrier();
    __builtin_amdgcn_sched_barrier(0);

    const ushort* L = lds + cur * 16384;
    f16x8 ah[4][2], bh[4][2];
#pragma unroll
    for (int t = 0; t < 4; ++t) {
      ah[t][0] = *(const f16x8*)&L[(wm + t * 16 + m15) * 32 + g * 8];
      ah[t][1] = *(const f16x8*)&L[4096 + (wm + t * 16 + m15) * 32 + g * 8];
      bh[t][0] = *(const f16x8*)&L[8192 + (wn + t * 16 + m15) * 32 + g * 8];
      bh[t][1] = *(const f16x8*)&L[12288 + (wn + t * 16 + m15) * 32 + g * 8];
    }
#pragma unroll
    for (int mi = 0; mi < 4; ++mi)
#pragma unroll
      for (int ni = 0; ni < 4; ++ni) {
        acc[mi][ni] = __builtin_amdgcn_mfma_f32_16x16x32_f16(ah[mi][0], bh[ni][0], acc[mi][ni], 0, 0, 0);
        acc[mi][ni] = __builtin_amdgcn_mfma_f32_16x16x32_f16(ah[mi][1], bh[ni][1], acc[mi][ni], 0, 0, 0);
      }
    __builtin_amdgcn_s_barrier();
    __builtin_amdgcn_sched_barrier(0);
  }
#pragma unroll
  for (int mi = 0; mi < 4; ++mi)
#pragma unroll
    for (int ni = 0; ni < 4; ++ni) {
      int col = n0 + wn + ni * 16 + m15;
#pragma unroll
      for (int r = 0; r < 4; ++r)
        C[(size_t)(m0 + wm + mi * 16 + g * 4 + r) * N + col] = acc[mi][ni][r] + bv[ni];
    }
}

// ------------- rotary + cast: Qb/Kb [h][s][96] (zero-padded); bf16 qkv in ----
__global__ __launch_bounds__(256)
void rotary_qk(const ushort* __restrict__ qkvb, const float* __restrict__ cosb,
               const float* __restrict__ sinb, ushort* __restrict__ Qb,
               ushort* __restrict__ Kb) {
  int id = blockIdx.x * 256 + threadIdx.x;
  int j = id % 48;
  int h = (id / 48) % NH;
  int s = id / (48 * NH);
  size_t qrow = (size_t)((h << 12) + s) * 96;
  if (j < 40) {
    size_t base = (size_t)s * QKV_N + h * HD;
    float c1 = cosb[s * HD + j],      s1 = sinb[s * HD + j];
    float c2 = cosb[s * HD + j + 40], s2 = sinb[s * HD + j + 40];
    const float QS = INV_SCALE * LOG2E;
    float q1 = bf2f(qkvb[base + j]), q2 = bf2f(qkvb[base + j + 40]);
    Qb[qrow + j]      = f2bf((q1 * c1 - q2 * s1) * QS);
    Qb[qrow + j + 40] = f2bf((q2 * c2 + q1 * s2) * QS);
    float k1 = bf2f(qkvb[base + HIDDEN + j]), k2 = bf2f(qkvb[base + HIDDEN + j + 40]);
    Kb[qrow + j]      = f2bf(k1 * c1 - k2 * s1);
    Kb[qrow + j + 40] = f2bf(k2 * c2 + k1 * s2);
  } else {
    int d = 80 + (j - 40) * 2;
    Qb[qrow + d] = 0; Qb[qrow + d + 1] = 0;
    Kb[qrow + d] = 0; Kb[qrow + d + 1] = 0;
  }
}

// ------- V transpose: qkvb v-section (bf16) -> VbT[h][80][4096] bf16 -------
__global__ __launch_bounds__(256)
void v_trans(const ushort* __restrict__ qkvb, ushort* __restrict__ VbT) {
  __shared__ ushort T[64][81];   // odd ushort stride: read phase conflict-free
  const int h = blockIdx.y, s0 = blockIdx.x * 64;
  for (int e = threadIdx.x; e < 5120; e += 256) {
    int r = e / 80, d = e % 80;
    T[r][d] = qkvb[(size_t)(s0 + r) * QKV_N + 2 * HIDDEN + h * HD + d];
  }
  __syncthreads();
  for (int e = threadIdx.x; e < 2560; e += 256) {
    int d = e >> 5, rp = (e & 31) * 2;
    ushort2 p;
    p.x = T[rp][d];
    p.y = T[rp + 1][d];
    *(ushort2*)&VbT[(size_t)h * 80 * SEQ + (size_t)d * SEQ + s0 + rp] = p;
  }
}

// ---- flash attention, bf16 MFMA, fixed-max softmax, fused normalize ----
// grid 512 x 256 threads (4 waves x 32 q-rows). VERIFIED R14 BODY (126us):
// XCD swizzle (FETCH 96->17.5MB), no setprio, no V-hoist.
// R16: epilogue writes a single fp16 ao buffer (proj GEMM is now fp16).
// Pipeline per iter (R8): issue 7 DMA chunks for t+1 -> s_waitcnt vmcnt(7)
// -> s_barrier -> compute t -> s_barrier. LDS 79,872 B -> 2 blocks/CU.
#define LPS 88    // Ps row stride (ushort)
#define LKS 104   // Ks row stride (ushort): 208 B = 13 chunks; 52 dw == 20 mod 32
#define LVS 88    // Vt row stride (ushort): 176 B = 11 chunks; 44 dw == 12 mod 32
__global__ __launch_bounds__(256, 2)
void attn_mfma(const ushort* __restrict__ Qb, const ushort* __restrict__ Kb,
               const ushort* __restrict__ VbT, ushort* __restrict__ ao16) {
  // [0,11264) ushorts: Ps[128][LPS] (22528 B)
  // buf b at byte 22528 + b*28672: Ks 64x[LKS] (13312 B) | Vt 80x[LVS] (14080 B)
  //   | pad 1280 B.  Total 22528 + 2*28672 = 79872 B.
  __shared__ __align__(16) ushort lds[39936];
  ushort* Ps = lds;
  char* ldsb = (char*)lds;

  const int tid = threadIdx.x, lane = tid & 63, w = tid >> 6;
  const int m15 = lane & 15, g = lane >> 4;
  const int idp = blockIdx.x;
  const int logical = (idp & 7) * 64 + (idp >> 3);   // XCD-contiguous
  const int h = logical >> 5, q0 = (logical & 31) * 128;
  const size_t hq = (size_t)h * SEQ * 96;
  const ushort* Qg = Qb + hq + (size_t)q0 * 96;
  const char* Kg = (const char*)(Kb + hq);
  const ushort* Vg = VbT + (size_t)h * 80 * SEQ;

  // ---- Q fragments straight from global (one-time, 6x16B per lane)
  bf16x8 qf[2][3];
#pragma unroll
  for (int mi = 0; mi < 2; ++mi)
#pragma unroll
    for (int c = 0; c < 3; ++c)
      qf[mi][c] = *(const bf16x8*)&Qg[(w * 32 + mi * 16 + m15) * 96 + c * 32 + g * 8];

  // ---- DMA source map: 1792 16B chunks/tile (K 832 | V 880 | pad 80), 7/thread.
  const char* sbase[7];
  int sstride[7];
#pragma unroll
  for (int i = 0; i < 7; ++i) {
    int c = tid + i * 256;
    if (c < 832) {
      int r = c / 13, cc = c - r * 13;
      sbase[i] = Kg + r * 192 + (cc == 12 ? 176 : cc * 16);
      sstride[i] = 192;                      // K tile advances kbase*192 bytes
    } else if (c < 1712) {
      int cv = c - 832;
      int r = cv / 11, cc = cv - r * 11;
      sbase[i] = (const char*)(Vg + (size_t)r * SEQ) + (cc >= 8 ? 112 : cc * 16);
      sstride[i] = 2;                        // V tile advances kbase*2 bytes
    } else {
      sbase[i] = Kg;
      sstride[i] = 192;
    }
  }
  const int dbase = 22528 + tid * 16;        // Ps bytes + lane-linear chunks

  // ---- prologue: issue DMA for tile 0 into buf0
#pragma unroll
  for (int i = 0; i < 7; ++i)
    async16(ldsb + dbase + i * 4096, sbase[i]);

  f32x4 o_[2][5];
#pragma unroll
  for (int mi = 0; mi < 2; ++mi)
#pragma unroll
    for (int n = 0; n < 5; ++n) o_[mi][n] = (f32x4){0.f, 0.f, 0.f, 0.f};
  float l_part[2] = {0.f, 0.f};

  const int NT = SEQ / 64;
  for (int kt = 0; kt < NT; ++kt) {
    const int cur = kt & 1;
    // ---- issue DMA for tile t+1 into buf^1 (clamped on last iter)
    {
      const size_t kn = (size_t)(((kt + 1 < NT) ? kt + 1 : kt) * 64);
      const int db = dbase + (cur ^ 1) * 28672;
#pragma unroll
      for (int i = 0; i < 7; ++i)
        async16(ldsb + db + i * 4096, sbase[i] + kn * sstride[i]);
    }
    // ---- wait own tile-t DMAs (t+1's 7 stay in flight), publish via barrier
    asm volatile("s_waitcnt vmcnt(7)" ::: "memory");
    __builtin_amdgcn_s_barrier();
    __builtin_amdgcn_sched_barrier(0);

    ushort* Ks = lds + 11264 + cur * 14336;
    ushort* Vt = Ks + 6656;

    // ---- S^T = K Q^T (log2-scaled): rows=key, col=q
    f32x4 st[2][4];
#pragma unroll
    for (int mi = 0; mi < 2; ++mi)
#pragma unroll
      for (int j = 0; j < 4; ++j) st[mi][j] = (f32x4){0.f, 0.f, 0.f, 0.f};
#pragma unroll
    for (int j = 0; j < 4; ++j)
#pragma unroll
      for (int c = 0; c < 3; ++c) {
        bf16x8 kf = *(const bf16x8*)&Ks[(j * 16 + m15) * LKS + c * 32 + g * 8];
        st[0][j] = __builtin_amdgcn_mfma_f32_16x16x32_bf16(kf, qf[0][c], st[0][j], 0, 0, 0);
        st[1][j] = __builtin_amdgcn_mfma_f32_16x16x32_bf16(kf, qf[1][c], st[1][j], 0, 0, 0);
      }
    // ---- p = exp2(s); accumulate l per-lane; pack & store P^T -> Ps[q][key]
#pragma unroll
    for (int mi = 0; mi < 2; ++mi) {
      float ls = 0.f;
#pragma unroll
      for (int j = 0; j < 4; ++j) {
        float p0 = __builtin_amdgcn_exp2f(st[mi][j][0]);
        float p1 = __builtin_amdgcn_exp2f(st[mi][j][1]);
        float p2 = __builtin_amdgcn_exp2f(st[mi][j][2]);
        float p3 = __builtin_amdgcn_exp2f(st[mi][j][3]);
        ls += (p0 + p1) + (p2 + p3);
        uint2 pw;
        pw.x = pk_bf16(p0, p1);
        pw.y = pk_bf16(p2, p3);
        *(uint2*)&Ps[(w * 32 + mi * 16 + m15) * LPS + j * 16 + g * 4] = pw;
      }
      l_part[mi] += ls;
    }
    // Ps rows are wave-private; order LDS writes before cross-lane reads.
    asm volatile("s_waitcnt lgkmcnt(0)" ::: "memory");
    // ---- O += P V
#pragma unroll
    for (int kc = 0; kc < 2; ++kc) {
      bf16x8 pf0 = *(const bf16x8*)&Ps[(w * 32 + m15) * LPS + kc * 32 + g * 8];
      bf16x8 pf1 = *(const bf16x8*)&Ps[(w * 32 + 16 + m15) * LPS + kc * 32 + g * 8];
#pragma unroll
      for (int n = 0; n < 5; ++n) {
        bf16x8 vf = *(const bf16x8*)&Vt[(n * 16 + m15) * LVS + kc * 32 + g * 8];
        o_[0][n] = __builtin_amdgcn_mfma_f32_16x16x32_bf16(pf0, vf, o_[0][n], 0, 0, 0);
        o_[1][n] = __builtin_amdgcn_mfma_f32_16x16x32_bf16(pf1, vf, o_[1][n], 0, 0, 0);
      }
    }
    // ---- all waves done reading buf[cur] before next iter's DMA overwrites it
    __builtin_amdgcn_s_barrier();
    __builtin_amdgcn_sched_barrier(0);
  }
  // ---- l: reduce over g-groups; redistribute to row-owners; normalize; cast
  float linv[2][4];
#pragma unroll
  for (int mi = 0; mi < 2; ++mi) {
    float t = l_part[mi];
    t += __shfl_xor(t, 16);
    t += __shfl_xor(t, 32);   // every lane: full l for q = w*32+mi*16+m15
#pragma unroll
    for (int r = 0; r < 4; ++r)
      linv[mi][r] = 1.f / __shfl(t, g * 4 + r);   // l for q-row g*4+r
  }
#pragma unroll
  for (int mi = 0; mi < 2; ++mi)
#pragma unroll
    for (int r = 0; r < 4; ++r) {
      int grow = q0 + w * 32 + mi * 16 + g * 4 + r;
      size_t base = (size_t)grow * HIDDEN + h * HD + m15;
#pragma unroll
      for (int n = 0; n < 5; ++n)
        ao16[base + n * 16] = f2h(o_[mi][n][r] * linv[mi][r]);
    }
}

extern "C" void kernel_launch(void* const* d_in, const int* in_sizes, int n_in,
                              void* d_out, int out_size, void* d_ws, size_t ws_size,
                              hipStream_t stream) {
  const float* x      = (const float*)d_in[0];
  const float* cosb   = (const float*)d_in[1];
  const float* sinb   = (const float*)d_in[2];
  const float* w_qkv  = (const float*)d_in[3];
  const float* b_qkv  = (const float*)d_in[4];
  const float* w_proj = (const float*)d_in[5];
  const float* b_proj = (const float*)d_in[6];
  float* out = (float*)d_out;

  // workspace layout (aliased; all kernels strictly ordered on `stream`):
  char* ws = (char*)d_ws;
  ushort* qkvb  = (ushort*)ws;                   // bf16 qkv, 30 MB; dead after v_trans
  ushort* ao16  = (ushort*)(ws + 42467328);      // fp16 attn out, 10,485,760
  size_t o = 62914560;
  ushort* xhi = (ushort*)(ws + o);               // 10.5 MB bf16 x
  ushort* Qb  = (ushort*)(ws + o);               // alias x-region after gemm1
  o += 20971520;
  ushort* wqT_h = (ushort*)(ws + o);             // 9.83 MB bf16 w_qkv^T
  ushort* Kb    = (ushort*)(ws + o);             // alias wqT after gemm1
  o += 19660800;
  ushort* VbT   = (ushort*)(ws + o); o += 10485760;   // 10.5 MB
  ushort* wpT16 = (ushort*)(ws + o);             // 3.28 MB fp16 w_proj^T
  // total ~90 MB

  // 1) casts
  split_rows<<<SEQ * HIDDEN / 1024, 256, 0, stream>>>(x, xhi, SEQ * HIDDEN);
  split_T<<<dim3(QKV_N / 32, HIDDEN / 32), 256, 0, stream>>>(w_qkv, wqT_h, HIDDEN, QKV_N);
  cast_T_f16<<<dim3(HIDDEN / 32, HIDDEN / 32), 256, 0, stream>>>(w_proj, wpT16, HIDDEN, HIDDEN);
  // 2) qkvb = bf16(x @ w_qkv + b_qkv)   (XCD-swizzled 1D grid: 960 blocks)
  gemm_bt_bf16<<<(QKV_N / 128) * (SEQ / 128), 256, 0, stream>>>(
      xhi, wqT_h, b_qkv, qkvb, SEQ, QKV_N, HIDDEN);
  // 3) rotary -> Qb/Kb; V transpose -> VbT  (qkvb dead afterwards)
  rotary_qk<<<SEQ * NH * 48 / 256, 256, 0, stream>>>(qkvb, cosb, sinb, Qb, Kb);
  v_trans<<<dim3(SEQ / 64, NH), 256, 0, stream>>>(qkvb, VbT);
  // 4) attention + fused normalize -> fp16 ao16 (XCD-swizzled 1D grid)
  attn_mfma<<<(SEQ / 128) * NH, 256, 0, stream>>>(Qb, Kb, VbT, ao16);
  // 5) out = ao16 @ w_proj + b_proj  (pure fp16 GEMM, XCD-swizzled, 320 blocks)
  gemm_bt_f16<<<(HIDDEN / 128) * (SEQ / 128), 256, 0, stream>>>(
      ao16, wpT16, b_proj, out, SEQ, HIDDEN, HIDDEN);
}

// Round 16
// 304.927 us; speedup vs baseline: 1.1886x; 1.0148x over previous
//
#include <hip/hip_runtime.h>
#include <hip/hip_bf16.h>

#define SEQ 4096
#define HIDDEN 1280
#define NH 16
#define HD 80
#define QKV_N 3840
#define INV_SCALE 0.11180339887498949f
#define LOG2E 1.4426950408889634f

typedef __attribute__((ext_vector_type(8))) short bf16x8;
typedef __attribute__((ext_vector_type(8))) _Float16 f16x8;
typedef __attribute__((ext_vector_type(4))) float f32x4;

__device__ __forceinline__ ushort f2bf(float f) {
  union { float f; unsigned u; } v; v.f = f;
  unsigned u = v.u;
  u += 0x7fff + ((u >> 16) & 1);   // RTNE
  return (ushort)(u >> 16);
}
__device__ __forceinline__ float bf2f(ushort h) {
  union { unsigned u; float f; } v; v.u = ((unsigned)h) << 16;
  return v.f;
}
__device__ __forceinline__ ushort f2h(float f) {
  union { _Float16 h; ushort u; } v; v.h = (_Float16)f;   // RTNE cvt
  return v.u;
}
__device__ __forceinline__ unsigned pk_bf16(float a, float b) {
  union { __hip_bfloat162 h; unsigned u; } v;
  v.h = __float22bfloat162_rn(make_float2(a, b));
  return v.u;
}
// async global->LDS, 16B per lane. LDS side must be base + lane*16 contiguous.
__device__ __forceinline__ void async16(void* lds, const void* g) {
  __builtin_amdgcn_global_load_lds(
      (const __attribute__((address_space(1))) unsigned*)g,
      (__attribute__((address_space(3))) unsigned*)(unsigned)(size_t)lds,
      16, 0, 0);
}

// -------- cast fp32 -> bf16, elementwise --------
__global__ __launch_bounds__(256)
void split_rows(const float* __restrict__ A, ushort* __restrict__ hi, int n) {
  int i = (blockIdx.x * 256 + threadIdx.x) * 4;
  if (i >= n) return;
  float4 v = *(const float4*)&A[i];
  ushort h[4];
  float x[4] = {v.x, v.y, v.z, v.w};
#pragma unroll
  for (int t = 0; t < 4; ++t) h[t] = f2bf(x[t]);
  *(ushort4*)&hi[i] = *(ushort4*)h;
}

// ---- cast + transpose: W[K][N] -> bf16 T [N][K] ----
__global__ __launch_bounds__(256)
void split_T(const float* __restrict__ W, ushort* __restrict__ hiT, int K, int N) {
  __shared__ float T[32][33];
  const int k0 = blockIdx.y * 32, n0 = blockIdx.x * 32;
  for (int e = threadIdx.x; e < 1024; e += 256) {
    int r = e >> 5, c = e & 31;
    T[r][c] = W[(size_t)(k0 + r) * N + n0 + c];
  }
  __syncthreads();
  for (int e = threadIdx.x; e < 1024; e += 256) {
    int r = e >> 5, c = e & 31;        // r: n-index, c: k-index
    hiT[(size_t)(n0 + r) * K + k0 + c] = f2bf(T[c][r]);
  }
}

// ---- cast + transpose: W[K][N] -> fp16 T [N][K] (proj weight) ----
__global__ __launch_bounds__(256)
void cast_T_f16(const float* __restrict__ W, ushort* __restrict__ T16, int K, int N) {
  __shared__ float T[32][33];
  const int k0 = blockIdx.y * 32, n0 = blockIdx.x * 32;
  for (int e = threadIdx.x; e < 1024; e += 256) {
    int r = e >> 5, c = e & 31;
    T[r][c] = W[(size_t)(k0 + r) * N + n0 + c];
  }
  __syncthreads();
  for (int e = threadIdx.x; e < 1024; e += 256) {
    int r = e >> 5, c = e & 31;
    T16[(size_t)(n0 + r) * K + k0 + c] = f2h(T[c][r]);
  }
}

// ------- pure-bf16 GEMM: Cb[M,N] = bf16(A[M,K] @ B^T[N,K] + bias) -------
// 128x128 tile, BK=64, 4 waves, DMA double-buffer + counted vmcnt + XCD swizzle.
__global__ __launch_bounds__(256, 2)
void gemm_bt_bf16(const ushort* __restrict__ Ab, const ushort* __restrict__ Bb,
                  const float* __restrict__ bias, ushort* __restrict__ Cb,
                  int M, int N, int K) {
  __shared__ __align__(16) ushort lds[32768];   // 2 bufs x (A0|A1|B0|B1, 8KB each)
  const int tid = threadIdx.x, lane = tid & 63, w = tid >> 6;
  const int m15 = lane & 15, g = lane >> 4;
  const int id = blockIdx.x;
  const int swz = (id & 7) * ((int)gridDim.x >> 3) + (id >> 3);
  const int nbx = N >> 7;
  const int m0 = (swz / nbx) * 128, n0 = (swz % nbx) * 128;
  const int wm = (w & 1) * 64, wn = (w >> 1) * 64;

  const ushort* stage_base =
      (w < 2) ? Ab + (size_t)m0 * K + (w & 1) * 32
              : Bb + (size_t)n0 * K + (w & 1) * 32;
  char* ldsb = (char*)lds;

  // bias first: oldest VMEM ops, drained by any later vmcnt
  float bv[4];
#pragma unroll
  for (int ni = 0; ni < 4; ++ni) bv[ni] = bias[n0 + wn + ni * 16 + m15];

  f32x4 acc[4][4];
#pragma unroll
  for (int i = 0; i < 4; ++i)
#pragma unroll
    for (int j = 0; j < 4; ++j) acc[i][j] = (f32x4){0.f, 0.f, 0.f, 0.f};

  const int NK = K >> 6;
  // prologue: tile 0 -> buf0
#pragma unroll
  for (int i = 0; i < 8; ++i) {
    int o = i * 1024 + lane * 16;      // byte offset within 8KB region
    int row = o >> 6, colb = o & 63;   // 64 B per row (32 bf16)
    async16(ldsb + w * 8192 + o, (const char*)(stage_base + (size_t)row * K) + colb);
  }
  for (int it = 0; it < NK; ++it) {
    const int cur = it & 1;
    const int kn = ((it + 1 < NK) ? it + 1 : it) * 64;
#pragma unroll
    for (int i = 0; i < 8; ++i) {
      int o = i * 1024 + lane * 16;
      int row = o >> 6, colb = o & 63;
      async16(ldsb + (cur ^ 1) * 32768 + w * 8192 + o,
              (const char*)(stage_base + (size_t)row * K + kn) + colb);
    }
    asm volatile("s_waitcnt vmcnt(8)" ::: "memory");
    __builtin_amdgcn_s_barrier();
    __builtin_amdgcn_sched_barrier(0);

    const ushort* L = lds + cur * 16384;
    bf16x8 ah[4][2], bh[4][2];
#pragma unroll
    for (int t = 0; t < 4; ++t) {
      ah[t][0] = *(const bf16x8*)&L[(wm + t * 16 + m15) * 32 + g * 8];
      ah[t][1] = *(const bf16x8*)&L[4096 + (wm + t * 16 + m15) * 32 + g * 8];
      bh[t][0] = *(const bf16x8*)&L[8192 + (wn + t * 16 + m15) * 32 + g * 8];
      bh[t][1] = *(const bf16x8*)&L[12288 + (wn + t * 16 + m15) * 32 + g * 8];
    }
#pragma unroll
    for (int mi = 0; mi < 4; ++mi)
#pragma unroll
      for (int ni = 0; ni < 4; ++ni) {
        acc[mi][ni] = __builtin_amdgcn_mfma_f32_16x16x32_bf16(ah[mi][0], bh[ni][0], acc[mi][ni], 0, 0, 0);
        acc[mi][ni] = __builtin_amdgcn_mfma_f32_16x16x32_bf16(ah[mi][1], bh[ni][1], acc[mi][ni], 0, 0, 0);
      }
    __builtin_amdgcn_s_barrier();
    __builtin_amdgcn_sched_barrier(0);
  }
#pragma unroll
  for (int mi = 0; mi < 4; ++mi)
#pragma unroll
    for (int ni = 0; ni < 4; ++ni) {
      int col = n0 + wn + ni * 16 + m15;
#pragma unroll
      for (int r = 0; r < 4; ++r)
        Cb[(size_t)(m0 + wm + mi * 16 + g * 4 + r) * N + col] =
            f2bf(acc[mi][ni][r] + bv[ni]);
    }
}

// ------- pure-fp16 GEMM: C[M,N] = A[M,K] @ B^T[N,K] + bias (fp32 out) -------
// Verified pipeline (BK=64, DMA dbuf, vmcnt(8), XCD swizzle) with f16 MFMA.
__global__ __launch_bounds__(256, 2)
void gemm_bt_f16(const ushort* __restrict__ Ab, const ushort* __restrict__ Bb,
                 const float* __restrict__ bias, float* __restrict__ C,
                 int M, int N, int K) {
  __shared__ __align__(16) ushort lds[32768];   // 2 bufs x (A0|A1|B0|B1, 8KB each)
  const int tid = threadIdx.x, lane = tid & 63, w = tid >> 6;
  const int m15 = lane & 15, g = lane >> 4;
  const int id = blockIdx.x;
  const int swz = (id & 7) * ((int)gridDim.x >> 3) + (id >> 3);
  const int nbx = N >> 7;
  const int m0 = (swz / nbx) * 128, n0 = (swz % nbx) * 128;
  const int wm = (w & 1) * 64, wn = (w >> 1) * 64;

  const ushort* stage_base =
      (w < 2) ? Ab + (size_t)m0 * K + (w & 1) * 32
              : Bb + (size_t)n0 * K + (w & 1) * 32;
  char* ldsb = (char*)lds;

  float bv[4];
#pragma unroll
  for (int ni = 0; ni < 4; ++ni) bv[ni] = bias[n0 + wn + ni * 16 + m15];

  f32x4 acc[4][4];
#pragma unroll
  for (int i = 0; i < 4; ++i)
#pragma unroll
    for (int j = 0; j < 4; ++j) acc[i][j] = (f32x4){0.f, 0.f, 0.f, 0.f};

  const int NK = K >> 6;
#pragma unroll
  for (int i = 0; i < 8; ++i) {
    int o = i * 1024 + lane * 16;
    int row = o >> 6, colb = o & 63;
    async16(ldsb + w * 8192 + o, (const char*)(stage_base + (size_t)row * K) + colb);
  }
  for (int it = 0; it < NK; ++it) {
    const int cur = it & 1;
    const int kn = ((it + 1 < NK) ? it + 1 : it) * 64;
#pragma unroll
    for (int i = 0; i < 8; ++i) {
      int o = i * 1024 + lane * 16;
      int row = o >> 6, colb = o & 63;
      async16(ldsb + (cur ^ 1) * 32768 + w * 8192 + o,
              (const char*)(stage_base + (size_t)row * K + kn) + colb);
    }
    asm volatile("s_waitcnt vmcnt(8)" ::: "memory");
    __builtin_amdgcn_s_barrier();
    __builtin_amdgcn_sched_barrier(0);

    const ushort* L = lds + cur * 16384;
    f16x8 ah[4][2], bh[4][2];
#pragma unroll
    for (int t = 0; t < 4; ++t) {
      ah[t][0] = *(const f16x8*)&L[(wm + t * 16 + m15) * 32 + g * 8];
      ah[t][1] = *(const f16x8*)&L[4096 + (wm + t * 16 + m15) * 32 + g * 8];
      bh[t][0] = *(const f16x8*)&L[8192 + (wn + t * 16 + m15) * 32 + g * 8];
      bh[t][1] = *(const f16x8*)&L[12288 + (wn + t * 16 + m15) * 32 + g * 8];
    }
#pragma unroll
    for (int mi = 0; mi < 4; ++mi)
#pragma unroll
      for (int ni = 0; ni < 4; ++ni) {
        acc[mi][ni] = __builtin_amdgcn_mfma_f32_16x16x32_f16(ah[mi][0], bh[ni][0], acc[mi][ni], 0, 0, 0);
        acc[mi][ni] = __builtin_amdgcn_mfma_f32_16x16x32_f16(ah[mi][1], bh[ni][1], acc[mi][ni], 0, 0, 0);
      }
    __builtin_amdgcn_s_barrier();
    __builtin_amdgcn_sched_barrier(0);
  }
#pragma unroll
  for (int mi = 0; mi < 4; ++mi)
#pragma unroll
    for (int ni = 0; ni < 4; ++ni) {
      int col = n0 + wn + ni * 16 + m15;
#pragma unroll
      for (int r = 0; r < 4; ++r)
        C[(size_t)(m0 + wm + mi * 16 + g * 4 + r) * N + col] = acc[mi][ni][r] + bv[ni];
    }
}

// ---- rotary + cast, VECTORIZED (R20): one thread per 4-wide j-group ----
// ushort4/float4 loads, ushort4 stores; 4.8x fewer threads than scalar version.
// grid = SEQ*NH*10/256 = 2560 blocks.
__global__ __launch_bounds__(256)
void rotary_qk(const ushort* __restrict__ qkvb, const float* __restrict__ cosb,
               const float* __restrict__ sinb, ushort* __restrict__ Qb,
               ushort* __restrict__ Kb) {
  int id = blockIdx.x * 256 + threadIdx.x;
  int jb = id % 10;
  int h = (id / 10) % NH;
  int s = id / (10 * NH);
  int j0 = jb * 4;
  size_t qrow = (size_t)((h << 12) + s) * 96;
  size_t base = (size_t)s * QKV_N + h * HD;

  ushort4 q1v = *(const ushort4*)&qkvb[base + j0];
  ushort4 q2v = *(const ushort4*)&qkvb[base + j0 + 40];
  ushort4 k1v = *(const ushort4*)&qkvb[base + HIDDEN + j0];
  ushort4 k2v = *(const ushort4*)&qkvb[base + HIDDEN + j0 + 40];
  float4 c1v = *(const float4*)&cosb[s * HD + j0];
  float4 s1v = *(const float4*)&sinb[s * HD + j0];
  float4 c2v = *(const float4*)&cosb[s * HD + j0 + 40];
  float4 s2v = *(const float4*)&sinb[s * HD + j0 + 40];

  float q1[4] = {bf2f(q1v.x), bf2f(q1v.y), bf2f(q1v.z), bf2f(q1v.w)};
  float q2[4] = {bf2f(q2v.x), bf2f(q2v.y), bf2f(q2v.z), bf2f(q2v.w)};
  float k1[4] = {bf2f(k1v.x), bf2f(k1v.y), bf2f(k1v.z), bf2f(k1v.w)};
  float k2[4] = {bf2f(k2v.x), bf2f(k2v.y), bf2f(k2v.z), bf2f(k2v.w)};
  float c1[4] = {c1v.x, c1v.y, c1v.z, c1v.w};
  float s1[4] = {s1v.x, s1v.y, s1v.z, s1v.w};
  float c2[4] = {c2v.x, c2v.y, c2v.z, c2v.w};
  float s2[4] = {s2v.x, s2v.y, s2v.z, s2v.w};

  const float QS = INV_SCALE * LOG2E;
  ushort qo1[4], qo2[4], ko1[4], ko2[4];
#pragma unroll
  for (int t = 0; t < 4; ++t) {
    qo1[t] = f2bf((q1[t] * c1[t] - q2[t] * s1[t]) * QS);
    qo2[t] = f2bf((q2[t] * c2[t] + q1[t] * s2[t]) * QS);
    ko1[t] = f2bf(k1[t] * c1[t] - k2[t] * s1[t]);
    ko2[t] = f2bf(k2[t] * c2[t] + k1[t] * s2[t]);
  }
  *(ushort4*)&Qb[qrow + j0]      = *(ushort4*)qo1;
  *(ushort4*)&Qb[qrow + j0 + 40] = *(ushort4*)qo2;
  *(ushort4*)&Kb[qrow + j0]      = *(ushort4*)ko1;
  *(ushort4*)&Kb[qrow + j0 + 40] = *(ushort4*)ko2;
  if (jb < 4) {   // zero-pad cols [80,96): 4 threads x ushort4
    ushort4 z = {0, 0, 0, 0};
    *(ushort4*)&Qb[qrow + 80 + jb * 4] = z;
    *(ushort4*)&Kb[qrow + 80 + jb * 4] = z;
  }
}

// ------- V transpose: qkvb v-section (bf16) -> VbT[h][80][4096] bf16 -------
// R20: load phase vectorized (ushort4 global reads); LDS stride 81 kept odd
// so the read/store phase stays conflict-free.
__global__ __launch_bounds__(256)
void v_trans(const ushort* __restrict__ qkvb, ushort* __restrict__ VbT) {
  __shared__ ushort T[64][81];
  const int h = blockIdx.y, s0 = blockIdx.x * 64;
  for (int e = threadIdx.x; e < 1280; e += 256) {
    int r = e / 20, d4 = (e % 20) * 4;
    ushort4 v = *(const ushort4*)&qkvb[(size_t)(s0 + r) * QKV_N + 2 * HIDDEN + h * HD + d4];
    T[r][d4] = v.x; T[r][d4 + 1] = v.y; T[r][d4 + 2] = v.z; T[r][d4 + 3] = v.w;
  }
  __syncthreads();
  for (int e = threadIdx.x; e < 2560; e += 256) {
    int d = e >> 5, rp = (e & 31) * 2;
    ushort2 p;
    p.x = T[rp][d];
    p.y = T[rp + 1][d];
    *(ushort2*)&VbT[(size_t)h * 80 * SEQ + (size_t)d * SEQ + s0 + rp] = p;
  }
}

// ---- flash attention, bf16 MFMA, fixed-max softmax, fused normalize ----
// grid 512 x 256 threads (4 waves x 32 q-rows). VERIFIED BODY (125us):
// XCD swizzle (FETCH 96->17.5MB), fp16 ao epilogue.
// Pipeline per iter (R8): issue 7 DMA chunks for t+1 -> s_waitcnt vmcnt(7)
// -> s_barrier -> compute t -> s_barrier. LDS 79,872 B -> 2 blocks/CU.
#define LPS 88    // Ps row stride (ushort)
#define LKS 104   // Ks row stride (ushort): 208 B = 13 chunks; 52 dw == 20 mod 32
#define LVS 88    // Vt row stride (ushort): 176 B = 11 chunks; 44 dw == 12 mod 32
__global__ __launch_bounds__(256, 2)
void attn_mfma(const ushort* __restrict__ Qb, const ushort* __restrict__ Kb,
               const ushort* __restrict__ VbT, ushort* __restrict__ ao16) {
  // [0,11264) ushorts: Ps[128][LPS] (22528 B)
  // buf b at byte 22528 + b*28672: Ks 64x[LKS] (13312 B) | Vt 80x[LVS] (14080 B)
  //   | pad 1280 B.  Total 22528 + 2*28672 = 79872 B.
  __shared__ __align__(16) ushort lds[39936];
  ushort* Ps = lds;
  char* ldsb = (char*)lds;

  const int tid = threadIdx.x, lane = tid & 63, w = tid >> 6;
  const int m15 = lane & 15, g = lane >> 4;
  const int idp = blockIdx.x;
  const int logical = (idp & 7) * 64 + (idp >> 3);   // XCD-contiguous
  const int h = logical >> 5, q0 = (logical & 31) * 128;
  const size_t hq = (size_t)h * SEQ * 96;
  const ushort* Qg = Qb + hq + (size_t)q0 * 96;
  const char* Kg = (const char*)(Kb + hq);
  const ushort* Vg = VbT + (size_t)h * 80 * SEQ;

  // ---- Q fragments straight from global (one-time, 6x16B per lane)
  bf16x8 qf[2][3];
#pragma unroll
  for (int mi = 0; mi < 2; ++mi)
#pragma unroll
    for (int c = 0; c < 3; ++c)
      qf[mi][c] = *(const bf16x8*)&Qg[(w * 32 + mi * 16 + m15) * 96 + c * 32 + g * 8];

  // ---- DMA source map: 1792 16B chunks/tile (K 832 | V 880 | pad 80), 7/thread.
  const char* sbase[7];
  int sstride[7];
#pragma unroll
  for (int i = 0; i < 7; ++i) {
    int c = tid + i * 256;
    if (c < 832) {
      int r = c / 13, cc = c - r * 13;
      sbase[i] = Kg + r * 192 + (cc == 12 ? 176 : cc * 16);
      sstride[i] = 192;                      // K tile advances kbase*192 bytes
    } else if (c < 1712) {
      int cv = c - 832;
      int r = cv / 11, cc = cv - r * 11;
      sbase[i] = (const char*)(Vg + (size_t)r * SEQ) + (cc >= 8 ? 112 : cc * 16);
      sstride[i] = 2;                        // V tile advances kbase*2 bytes
    } else {
      sbase[i] = Kg;
      sstride[i] = 192;
    }
  }
  const int dbase = 22528 + tid * 16;        // Ps bytes + lane-linear chunks

  // ---- prologue: issue DMA for tile 0 into buf0
#pragma unroll
  for (int i = 0; i < 7; ++i)
    async16(ldsb + dbase + i * 4096, sbase[i]);

  f32x4 o_[2][5];
#pragma unroll
  for (int mi = 0; mi < 2; ++mi)
#pragma unroll
    for (int n = 0; n < 5; ++n) o_[mi][n] = (f32x4){0.f, 0.f, 0.f, 0.f};
  float l_part[2] = {0.f, 0.f};

  const int NT = SEQ / 64;
  for (int kt = 0; kt < NT; ++kt) {
    const int cur = kt & 1;
    // ---- issue DMA for tile t+1 into buf^1 (clamped on last iter)
    {
      const size_t kn = (size_t)(((kt + 1 < NT) ? kt + 1 : kt) * 64);
      const int db = dbase + (cur ^ 1) * 28672;
#pragma unroll
      for (int i = 0; i < 7; ++i)
        async16(ldsb + db + i * 4096, sbase[i] + kn * sstride[i]);
    }
    // ---- wait own tile-t DMAs (t+1's 7 stay in flight), publish via barrier
    asm volatile("s_waitcnt vmcnt(7)" ::: "memory");
    __builtin_amdgcn_s_barrier();
    __builtin_amdgcn_sched_barrier(0);

    ushort* Ks = lds + 11264 + cur * 14336;
    ushort* Vt = Ks + 6656;

    // ---- S^T = K Q^T (log2-scaled): rows=key, col=q
    f32x4 st[2][4];
#pragma unroll
    for (int mi = 0; mi < 2; ++mi)
#pragma unroll
      for (int j = 0; j < 4; ++j) st[mi][j] = (f32x4){0.f, 0.f, 0.f, 0.f};
#pragma unroll
    for (int j = 0; j < 4; ++j)
#pragma unroll
      for (int c = 0; c < 3; ++c) {
        bf16x8 kf = *(const bf16x8*)&Ks[(j * 16 + m15) * LKS + c * 32 + g * 8];
        st[0][j] = __builtin_amdgcn_mfma_f32_16x16x32_bf16(kf, qf[0][c], st[0][j], 0, 0, 0);
        st[1][j] = __builtin_amdgcn_mfma_f32_16x16x32_bf16(kf, qf[1][c], st[1][j], 0, 0, 0);
      }
    // ---- p = exp2(s); accumulate l per-lane; pack & store P^T -> Ps[q][key]
#pragma unroll
    for (int mi = 0; mi < 2; ++mi) {
      float ls = 0.f;
#pragma unroll
      for (int j = 0; j < 4; ++j) {
        float p0 = __builtin_amdgcn_exp2f(st[mi][j][0]);
        float p1 = __builtin_amdgcn_exp2f(st[mi][j][1]);
        float p2 = __builtin_amdgcn_exp2f(st[mi][j][2]);
        float p3 = __builtin_amdgcn_exp2f(st[mi][j][3]);
        ls += (p0 + p1) + (p2 + p3);
        uint2 pw;
        pw.x = pk_bf16(p0, p1);
        pw.y = pk_bf16(p2, p3);
        *(uint2*)&Ps[(w * 32 + mi * 16 + m15) * LPS + j * 16 + g * 4] = pw;
      }
      l_part[mi] += ls;
    }
    // Ps rows are wave-private; order LDS writes before cross-lane reads.
    asm volatile("s_waitcnt lgkmcnt(0)" ::: "memory");
    // ---- O += P V
#pragma unroll
    for (int kc = 0; kc < 2; ++kc) {
      bf16x8 pf0 = *(const bf16x8*)&Ps[(w * 32 + m15) * LPS + kc * 32 + g * 8];
      bf16x8 pf1 = *(const bf16x8*)&Ps[(w * 32 + 16 + m15) * LPS + kc * 32 + g * 8];
#pragma unroll
      for (int n = 0; n < 5; ++n) {
        bf16x8 vf = *(const bf16x8*)&Vt[(n * 16 + m15) * LVS + kc * 32 + g * 8];
        o_[0][n] = __builtin_amdgcn_mfma_f32_16x16x32_bf16(pf0, vf, o_[0][n], 0, 0, 0);
        o_[1][n] = __builtin_amdgcn_mfma_f32_16x16x32_bf16(pf1, vf, o_[1][n], 0, 0, 0);
      }
    }
    // ---- all waves done reading buf[cur] before next iter's DMA overwrites it
    __builtin_amdgcn_s_barrier();
    __builtin_amdgcn_sched_barrier(0);
  }
  // ---- l: reduce over g-groups; redistribute to row-owners; normalize; cast
  float linv[2][4];
#pragma unroll
  for (int mi = 0; mi < 2; ++mi) {
    float t = l_part[mi];
    t += __shfl_xor(t, 16);
    t += __shfl_xor(t, 32);   // every lane: full l for q = w*32+mi*16+m15
#pragma unroll
    for (int r = 0; r < 4; ++r)
      linv[mi][r] = 1.f / __shfl(t, g * 4 + r);   // l for q-row g*4+r
  }
#pragma unroll
  for (int mi = 0; mi < 2; ++mi)
#pragma unroll
    for (int r = 0; r < 4; ++r) {
      int grow = q0 + w * 32 + mi * 16 + g * 4 + r;
      size_t base = (size_t)grow * HIDDEN + h * HD + m15;
#pragma unroll
      for (int n = 0; n < 5; ++n)
        ao16[base + n * 16] = f2h(o_[mi][n][r] * linv[mi][r]);
    }
}

extern "C" void kernel_launch(void* const* d_in, const int* in_sizes, int n_in,
                              void* d_out, int out_size, void* d_ws, size_t ws_size,
                              hipStream_t stream) {
  const float* x      = (const float*)d_in[0];
  const float* cosb   = (const float*)d_in[1];
  const float* sinb   = (const float*)d_in[2];
  const float* w_qkv  = (const float*)d_in[3];
  const float* b_qkv  = (const float*)d_in[4];
  const float* w_proj = (const float*)d_in[5];
  const float* b_proj = (const float*)d_in[6];
  float* out = (float*)d_out;

  // workspace layout (aliased; all kernels strictly ordered on `stream`):
  char* ws = (char*)d_ws;
  ushort* qkvb  = (ushort*)ws;                   // bf16 qkv, 30 MB; dead after v_trans
  ushort* ao16  = (ushort*)(ws + 42467328);      // fp16 attn out, 10,485,760
  size_t o = 62914560;
  ushort* xhi = (ushort*)(ws + o);               // 10.5 MB bf16 x
  ushort* Qb  = (ushort*)(ws + o);               // alias x-region after gemm1
  o += 20971520;
  ushort* wqT_h = (ushort*)(ws + o);             // 9.83 MB bf16 w_qkv^T
  ushort* Kb    = (ushort*)(ws + o);             // alias wqT after gemm1
  o += 19660800;
  ushort* VbT   = (ushort*)(ws + o); o += 10485760;   // 10.5 MB
  ushort* wpT16 = (ushort*)(ws + o);             // 3.28 MB fp16 w_proj^T
  // total ~90 MB

  // 1) casts
  split_rows<<<SEQ * HIDDEN / 1024, 256, 0, stream>>>(x, xhi, SEQ * HIDDEN);
  split_T<<<dim3(QKV_N / 32, HIDDEN / 32), 256, 0, stream>>>(w_qkv, wqT_h, HIDDEN, QKV_N);
  cast_T_f16<<<dim3(HIDDEN / 32, HIDDEN / 32), 256, 0, stream>>>(w_proj, wpT16, HIDDEN, HIDDEN);
  // 2) qkvb = bf16(x @ w_qkv + b_qkv)   (XCD-swizzled 1D grid: 960 blocks)
  gemm_bt_bf16<<<(QKV_N / 128) * (SEQ / 128), 256, 0, stream>>>(
      xhi, wqT_h, b_qkv, qkvb, SEQ, QKV_N, HIDDEN);
  // 3) rotary (vectorized) -> Qb/Kb; V transpose -> VbT  (qkvb dead afterwards)
  rotary_qk<<<SEQ * NH * 10 / 256, 256, 0, stream>>>(qkvb, cosb, sinb, Qb, Kb);
  v_trans<<<dim3(SEQ / 64, NH), 256, 0, stream>>>(qkvb, VbT);
  // 4) attention + fused normalize -> fp16 ao16 (XCD-swizzled 1D grid)
  attn_mfma<<<(SEQ / 128) * NH, 256, 0, stream>>>(Qb, Kb, VbT, ao16);
  // 5) out = ao16 @ w_proj + b_proj  (pure fp16 GEMM, XCD-swizzled, 320 blocks)
  gemm_bt_f16<<<(HIDDEN / 128) * (SEQ / 128), 256, 0, stream>>>(
      ao16, wpT16, b_proj, out, SEQ, HIDDEN, HIDDEN);
}